// Round 1
// baseline (587.779 us; speedup 1.0000x reference)
//
#include <hip/hip_runtime.h>
#include <hip/hip_bf16.h>

#define N_NODES 10000
#define M_PAD   10112   // 79*128, so GEMM M-tiles need no guards
#define F_IN    128
#define H_DIM   512
#define N_CLS   7

// ---------------- CSR build ----------------

__global__ void k_zero_i32(int* __restrict__ p, int n) {
    int i = blockIdx.x * blockDim.x + threadIdx.x;
    if (i < n) p[i] = 0;
}

__global__ void k_hist(const int* __restrict__ ei, int* __restrict__ counts, int E) {
    int e = blockIdx.x * blockDim.x + threadIdx.x;
    if (e < E) atomicAdd(&counts[ei[E + e]], 1);  // dst = ei[E+e]
}

__global__ __launch_bounds__(1024) void k_scan(const int* __restrict__ counts,
                                               int* __restrict__ offsets,
                                               int* __restrict__ cursor,
                                               int N, int E) {
    __shared__ int sm[1024];
    int t = threadIdx.x;
    int base = t * 10;
    int loc[10];
    int s = 0;
    #pragma unroll
    for (int i = 0; i < 10; ++i) {
        int idx = base + i;
        int c = (idx < N) ? counts[idx] : 0;
        loc[i] = s;
        s += c;
    }
    sm[t] = s;
    __syncthreads();
    for (int off = 1; off < 1024; off <<= 1) {
        int v = (t >= off) ? sm[t - off] : 0;
        __syncthreads();
        sm[t] += v;
        __syncthreads();
    }
    int excl = sm[t] - s;  // exclusive prefix of this thread's chunk
    #pragma unroll
    for (int i = 0; i < 10; ++i) {
        int idx = base + i;
        if (idx < N) {
            int o = excl + loc[i];
            offsets[idx] = o;
            cursor[idx] = o;
        }
    }
    if (t == 0) offsets[N] = E;
}

__global__ void k_scatter(const int* __restrict__ ei, int* __restrict__ cursor,
                          int* __restrict__ csr_src, int E) {
    int e = blockIdx.x * blockDim.x + threadIdx.x;
    if (e < E) {
        int d = ei[E + e];
        int pos = atomicAdd(&cursor[d], 1);
        csr_src[pos] = ei[e];  // src
    }
}

// ---------------- GIN aggregation: out[n] = (1+eps)*X[n] + sum_{src->n} X[src] ----------------

template <int F>
__global__ void k_agg(const float* __restrict__ X, const int* __restrict__ csr_src,
                      const int* __restrict__ offsets, const float* __restrict__ eps,
                      float* __restrict__ out) {
    int n = blockIdx.x;
    int f = threadIdx.x;
    int s0 = offsets[n], s1 = offsets[n + 1];
    float s = 0.f;
    for (int i = s0; i < s1; ++i) {
        int src = csr_src[i];
        s += X[(size_t)src * F + f];
    }
    out[(size_t)n * F + f] = (1.0f + eps[0]) * X[(size_t)n * F + f] + s;
}

// ---------------- GEMM: C = epilogue(A @ W + bias), 128x128 tile, 8x8/thread ----------------
// EP==0: relu;  EP==1: bn(relu(.))  with bn eval: v*s + (be - rm*s), s = g*rsqrt(rv+eps)

template <int EP>
__global__ __launch_bounds__(256) void k_gemm(
    const float* __restrict__ A, const float* __restrict__ W,
    const float* __restrict__ bias,
    const float* __restrict__ g, const float* __restrict__ be,
    const float* __restrict__ rm, const float* __restrict__ rv,
    float* __restrict__ C, int M, int N, int K) {
    __shared__ float As[16][128];  // As[kk][m]
    __shared__ float Ws[16][128];  // Ws[kk][n]
    const int tid = threadIdx.x;
    const int bm = blockIdx.x * 128;
    const int bn = blockIdx.y * 128;
    const int tx = tid & 15;
    const int ty = tid >> 4;

    float acc[8][8];
    #pragma unroll
    for (int i = 0; i < 8; ++i)
        #pragma unroll
        for (int j = 0; j < 8; ++j) acc[i][j] = 0.f;

    for (int k0 = 0; k0 < K; k0 += 16) {
        #pragma unroll
        for (int l = 0; l < 2; ++l) {
            int idx = tid + l * 256;   // 0..511
            int row = idx >> 2;        // 0..127
            int q = idx & 3;
            float4 v = *reinterpret_cast<const float4*>(A + (size_t)(bm + row) * K + k0 + q * 4);
            As[q * 4 + 0][row] = v.x;
            As[q * 4 + 1][row] = v.y;
            As[q * 4 + 2][row] = v.z;
            As[q * 4 + 3][row] = v.w;
        }
        #pragma unroll
        for (int l = 0; l < 2; ++l) {
            int idx = tid + l * 256;
            int kk = idx >> 5;   // 0..15
            int nq = idx & 31;   // float4 within row
            *reinterpret_cast<float4*>(&Ws[kk][nq * 4]) =
                *reinterpret_cast<const float4*>(W + (size_t)(k0 + kk) * N + bn + nq * 4);
        }
        __syncthreads();
        #pragma unroll
        for (int kk = 0; kk < 16; ++kk) {
            float a[8], b[8];
            *reinterpret_cast<float4*>(&a[0]) = *reinterpret_cast<const float4*>(&As[kk][ty * 8]);
            *reinterpret_cast<float4*>(&a[4]) = *reinterpret_cast<const float4*>(&As[kk][ty * 8 + 4]);
            *reinterpret_cast<float4*>(&b[0]) = *reinterpret_cast<const float4*>(&Ws[kk][tx * 8]);
            *reinterpret_cast<float4*>(&b[4]) = *reinterpret_cast<const float4*>(&Ws[kk][tx * 8 + 4]);
            #pragma unroll
            for (int i = 0; i < 8; ++i)
                #pragma unroll
                for (int j = 0; j < 8; ++j) acc[i][j] = fmaf(a[i], b[j], acc[i][j]);
        }
        __syncthreads();
    }

    float bs[8], sc[8], sh[8];
    #pragma unroll
    for (int j = 0; j < 8; ++j) {
        int col = bn + tx * 8 + j;
        bs[j] = bias[col];
        if (EP == 1) {
            float s = g[col] * rsqrtf(rv[col] + 1e-5f);
            sc[j] = s;
            sh[j] = be[col] - rm[col] * s;
        }
    }
    #pragma unroll
    for (int i = 0; i < 8; ++i) {
        int row = bm + ty * 8 + i;
        float o[8];
        #pragma unroll
        for (int j = 0; j < 8; ++j) {
            float v = fmaxf(acc[i][j] + bs[j], 0.f);
            if (EP == 1) v = v * sc[j] + sh[j];
            o[j] = v;
        }
        float* dst = C + (size_t)row * N + bn + tx * 8;
        *reinterpret_cast<float4*>(dst) = *reinterpret_cast<float4*>(&o[0]);
        *reinterpret_cast<float4*>(dst + 4) = *reinterpret_cast<float4*>(&o[4]);
    }
}

// ---------------- edge head: out[t] = (h[a] * h[b]) @ Wf + bf ----------------

__global__ __launch_bounds__(256) void k_edge(
    const float* __restrict__ h, const int* __restrict__ ei,
    const int* __restrict__ tids, const float* __restrict__ Wf,
    const float* __restrict__ bf, float* __restrict__ out, int Etr, int E) {
    __shared__ float wf[H_DIM * N_CLS];
    for (int i = threadIdx.x; i < H_DIM * N_CLS; i += 256) wf[i] = Wf[i];
    __syncthreads();
    int wave = threadIdx.x >> 6;
    int lane = threadIdx.x & 63;
    int t = blockIdx.x * 4 + wave;
    if (t >= Etr) return;
    int eid = tids[t];
    int a = ei[eid];
    int b = ei[E + eid];
    const float* ha = h + (size_t)a * H_DIM;
    const float* hb = h + (size_t)b * H_DIM;
    float acc[N_CLS] = {0.f, 0.f, 0.f, 0.f, 0.f, 0.f, 0.f};
    #pragma unroll
    for (int j = 0; j < H_DIM / 64; ++j) {
        int k = j * 64 + lane;
        float e = ha[k] * hb[k];
        #pragma unroll
        for (int c = 0; c < N_CLS; ++c) acc[c] = fmaf(e, wf[k * N_CLS + c], acc[c]);
    }
    #pragma unroll
    for (int off = 32; off; off >>= 1)
        #pragma unroll
        for (int c = 0; c < N_CLS; ++c) acc[c] += __shfl_xor(acc[c], off, 64);
    if (lane == 0) {
        #pragma unroll
        for (int c = 0; c < N_CLS; ++c) out[(size_t)t * N_CLS + c] = acc[c] + bf[c];
    }
}

// ---------------- launch ----------------

extern "C" void kernel_launch(void* const* d_in, const int* in_sizes, int n_in,
                              void* d_out, int out_size, void* d_ws, size_t ws_size,
                              hipStream_t stream) {
    const float* x    = (const float*)d_in[0];
    const int*   ei   = (const int*)d_in[1];
    const int*   tids = (const int*)d_in[2];
    const float* eps1 = (const float*)d_in[3];
    const float* W1a  = (const float*)d_in[4];
    const float* b1a  = (const float*)d_in[5];
    const float* W1b  = (const float*)d_in[6];
    const float* b1b  = (const float*)d_in[7];
    const float* g1p  = (const float*)d_in[8];
    const float* be1  = (const float*)d_in[9];
    const float* rm1  = (const float*)d_in[10];
    const float* rv1  = (const float*)d_in[11];
    const float* eps2 = (const float*)d_in[12];
    const float* W2a  = (const float*)d_in[13];
    const float* b2a  = (const float*)d_in[14];
    const float* g2p  = (const float*)d_in[15];
    const float* be2  = (const float*)d_in[16];
    const float* rm2  = (const float*)d_in[17];
    const float* rv2  = (const float*)d_in[18];
    const float* Wl   = (const float*)d_in[19];
    const float* bl   = (const float*)d_in[20];
    const float* Wf   = (const float*)d_in[21];
    const float* bf   = (const float*)d_in[22];
    float* out = (float*)d_out;

    const int E   = in_sizes[1] / 2;
    const int Etr = in_sizes[2];

    char* ws = (char*)d_ws;
    size_t off = 0;
    auto alloc = [&](size_t bytes) -> char* {
        char* p = ws + off;
        off += (bytes + 255) & ~(size_t)255;
        return p;
    };
    int*   counts  = (int*)alloc((size_t)N_NODES * 4);
    int*   offsets = (int*)alloc((size_t)(N_NODES + 1) * 4);
    int*   cursor  = (int*)alloc((size_t)N_NODES * 4);
    int*   csr_src = (int*)alloc((size_t)E * 4);
    float* h0      = (float*)alloc((size_t)M_PAD * F_IN * 4);
    float* B1      = (float*)alloc((size_t)M_PAD * H_DIM * 4);
    float* B2      = (float*)alloc((size_t)M_PAD * H_DIM * 4);
    (void)ws_size; (void)n_in; (void)out_size;

    // CSR by dst
    k_zero_i32<<<(N_NODES + 255) / 256, 256, 0, stream>>>(counts, N_NODES);
    k_hist<<<(E + 255) / 256, 256, 0, stream>>>(ei, counts, E);
    k_scan<<<1, 1024, 0, stream>>>(counts, offsets, cursor, N_NODES, E);
    k_scatter<<<(E + 255) / 256, 256, 0, stream>>>(ei, cursor, csr_src, E);

    // h0 = (1+eps1)*x + agg(x)            (rows >= N_NODES stay poison; row-contained, never read)
    k_agg<F_IN><<<N_NODES, F_IN, 0, stream>>>(x, csr_src, offsets, eps1, h0);

    dim3 gdim(M_PAD / 128, H_DIM / 128);
    // h1 = relu(h0 @ W1a + b1a)           -> B1
    k_gemm<0><<<gdim, 256, 0, stream>>>(h0, W1a, b1a, nullptr, nullptr, nullptr, nullptr,
                                        B1, M_PAD, H_DIM, F_IN);
    // h2 = bn1(relu(h1 @ W1b + b1b))      -> B2
    k_gemm<1><<<gdim, 256, 0, stream>>>(B1, W1b, b1b, g1p, be1, rm1, rv1,
                                        B2, M_PAD, H_DIM, H_DIM);
    // h3 = (1+eps2)*h2 + agg(h2)          -> B1
    k_agg<H_DIM><<<N_NODES, H_DIM, 0, stream>>>(B2, csr_src, offsets, eps2, B1);
    // h4 = bn2(relu(h3 @ W2a + b2a))      -> B2
    k_gemm<1><<<gdim, 256, 0, stream>>>(B1, W2a, b2a, g2p, be2, rm2, rv2,
                                        B2, M_PAD, H_DIM, H_DIM);
    // h5 = relu(h4 @ Wl + bl)             -> B1
    k_gemm<0><<<gdim, 256, 0, stream>>>(B2, Wl, bl, nullptr, nullptr, nullptr, nullptr,
                                        B1, M_PAD, H_DIM, H_DIM);
    // edge head
    k_edge<<<(Etr + 3) / 4, 256, 0, stream>>>(B1, ei, tids, Wf, bf, out, Etr, E);
}

// Round 7
// 373.711 us; speedup vs baseline: 1.5728x; 1.5728x over previous
//
#include <hip/hip_runtime.h>
#include <hip/hip_bf16.h>

#define N_NODES 10000
#define M_PAD   10112   // 79*128
#define F_IN    128
#define H_DIM   512
#define N_CLS   7

typedef __bf16 bf16x8 __attribute__((ext_vector_type(8)));
typedef float  f32x4  __attribute__((ext_vector_type(4)));

__device__ __forceinline__ ushort f2bf(float f) {
    union { float f; unsigned u; } x; x.f = f;
    unsigned r = x.u + 0x7fffu + ((x.u >> 16) & 1u);
    return (ushort)(r >> 16);
}
__device__ __forceinline__ float bf2f(ushort h) {
    union { unsigned u; float f; } x; x.u = ((unsigned)h) << 16;
    return x.f;
}

__device__ __forceinline__ void gload16(const void* g, void* l) {
    __builtin_amdgcn_global_load_lds(
        (const __attribute__((address_space(1))) void*)g,
        (__attribute__((address_space(3))) void*)l, 16, 0, 0);
}

// ---------------- CSR build ----------------

__global__ void k_zero_i32(int* __restrict__ p, int n) {
    int i = blockIdx.x * blockDim.x + threadIdx.x;
    if (i < n) p[i] = 0;
}

__global__ void k_hist(const int* __restrict__ ei, int* __restrict__ counts, int E) {
    int e = blockIdx.x * blockDim.x + threadIdx.x;
    if (e < E) atomicAdd(&counts[ei[E + e]], 1);  // dst
}

__global__ __launch_bounds__(1024) void k_scan(const int* __restrict__ counts,
                                               int* __restrict__ offsets,
                                               int* __restrict__ cursor,
                                               int N, int E) {
    __shared__ int sm[1024];
    int t = threadIdx.x;
    int base = t * 10;
    int loc[10];
    int s = 0;
    #pragma unroll
    for (int i = 0; i < 10; ++i) {
        int idx = base + i;
        int c = (idx < N) ? counts[idx] : 0;
        loc[i] = s;
        s += c;
    }
    sm[t] = s;
    __syncthreads();
    for (int off = 1; off < 1024; off <<= 1) {
        int v = (t >= off) ? sm[t - off] : 0;
        __syncthreads();
        sm[t] += v;
        __syncthreads();
    }
    int excl = sm[t] - s;
    #pragma unroll
    for (int i = 0; i < 10; ++i) {
        int idx = base + i;
        if (idx < N) {
            int o = excl + loc[i];
            offsets[idx] = o;
            cursor[idx] = o;
        }
    }
    if (t == 0) offsets[N] = E;
}

__global__ void k_scatter(const int* __restrict__ ei, int* __restrict__ cursor,
                          int* __restrict__ csr_src, int E) {
    int e = blockIdx.x * blockDim.x + threadIdx.x;
    if (e < E) {
        int d = ei[E + e];
        int pos = atomicAdd(&cursor[d], 1);
        csr_src[pos] = ei[e];
    }
}

// ---------------- weight split: W (K x N fp32) -> Wt_hi/Wt_lo (N x K bf16) ----------------

__global__ void k_wsplit(const float* __restrict__ W, ushort* __restrict__ Th,
                         ushort* __restrict__ Tl, int K, int N) {
    int idx = blockIdx.x * blockDim.x + threadIdx.x;
    if (idx >= K * N) return;
    int n = idx / K, k = idx % K;
    float w = W[(size_t)k * N + n];
    ushort hb = f2bf(w);
    Th[idx] = hb;
    Tl[idx] = f2bf(w - bf2f(hb));
}

// ---------------- GIN agg, fp32 input (F=128): out pair = (1+eps)*X + sum nbrs ----------------

__global__ __launch_bounds__(128) void k_agg_f32(
    const float* __restrict__ X, const int* __restrict__ csr,
    const int* __restrict__ offs, const float* __restrict__ eps,
    ushort* __restrict__ Oh, ushort* __restrict__ Ol) {
    const int n = blockIdx.x, f = threadIdx.x;
    const int s0 = offs[n], s1 = offs[n + 1];
    float s = 0.f;
    for (int i = s0; i < s1; ++i) s += X[(size_t)csr[i] * F_IN + f];
    const float v = (1.f + eps[0]) * X[(size_t)n * F_IN + f] + s;
    const ushort hb = f2bf(v);
    const size_t o = (size_t)n * F_IN + f;
    Oh[o] = hb;
    Ol[o] = f2bf(v - bf2f(hb));
}

// ---------------- GIN agg, pair input (F=512), 128 thr x 4 cols ----------------

__global__ __launch_bounds__(128) void k_agg_pair(
    const ushort* __restrict__ Xh, const ushort* __restrict__ Xl,
    const int* __restrict__ csr, const int* __restrict__ offs,
    const float* __restrict__ eps,
    ushort* __restrict__ Oh, ushort* __restrict__ Ol) {
    const int n = blockIdx.x;
    const size_t c0 = (size_t)threadIdx.x * 4;
    const int s0 = offs[n], s1 = offs[n + 1];
    float a0 = 0.f, a1 = 0.f, a2 = 0.f, a3 = 0.f;
    for (int i = s0; i < s1; ++i) {
        const size_t b = (size_t)csr[i] * H_DIM + c0;
        ushort4 h = *(const ushort4*)(Xh + b);
        ushort4 l = *(const ushort4*)(Xl + b);
        a0 += bf2f(h.x) + bf2f(l.x);
        a1 += bf2f(h.y) + bf2f(l.y);
        a2 += bf2f(h.z) + bf2f(l.z);
        a3 += bf2f(h.w) + bf2f(l.w);
    }
    const size_t b = (size_t)n * H_DIM + c0;
    ushort4 h = *(const ushort4*)(Xh + b);
    ushort4 l = *(const ushort4*)(Xl + b);
    const float e = 1.f + eps[0];
    float v0 = e * (bf2f(h.x) + bf2f(l.x)) + a0;
    float v1 = e * (bf2f(h.y) + bf2f(l.y)) + a1;
    float v2 = e * (bf2f(h.z) + bf2f(l.z)) + a2;
    float v3 = e * (bf2f(h.w) + bf2f(l.w)) + a3;
    ushort4 oh, ol;
    oh.x = f2bf(v0); ol.x = f2bf(v0 - bf2f(oh.x));
    oh.y = f2bf(v1); ol.y = f2bf(v1 - bf2f(oh.y));
    oh.z = f2bf(v2); ol.z = f2bf(v2 - bf2f(oh.z));
    oh.w = f2bf(v3); ol.w = f2bf(v3 - bf2f(oh.w));
    *(ushort4*)(Oh + b) = oh;
    *(ushort4*)(Ol + b) = ol;
}

// ---------------- split-bf16 MFMA GEMM ----------------
// C = ep(A @ W + bias); A as hi/lo pair (M x K), W as hi/lo pair transposed [N][K].
// 128x128 tile, BK=32, 4 waves 2x2 (64x64 each), mfma_f32_16x16x32_bf16.
// 3 MFMA terms per frag-pair: hi*hi + hi*lo + lo*hi  (drop lo*lo ~2^-16).
// ep: relu, then optional BN: v*s + (be - rm*s), s = g*rsqrt(rv+1e-5).
// Output written as hi/lo bf16 pair.

template <int DO_BN>
__global__ __launch_bounds__(256) void k_gemm_mfma(
    const ushort* __restrict__ Ah, const ushort* __restrict__ Al,
    const ushort* __restrict__ Wh, const ushort* __restrict__ Wlo,
    const float* __restrict__ bias,
    const float* __restrict__ g, const float* __restrict__ be,
    const float* __restrict__ rm, const float* __restrict__ rv,
    ushort* __restrict__ Oh, ushort* __restrict__ Ol,
    int K, int Nout) {
    __shared__ __align__(16) ushort As_h[128][32];
    __shared__ __align__(16) ushort As_l[128][32];
    __shared__ __align__(16) ushort Bs_h[128][32];
    __shared__ __align__(16) ushort Bs_l[128][32];

    const int tid  = threadIdx.x;
    const int lane = tid & 63;
    const int wid  = tid >> 6;
    const int wm   = wid >> 1, wn = wid & 1;
    const int bm = blockIdx.x * 128, bn = blockIdx.y * 128;
    const int rsel = lane & 15;
    const int kh   = (lane >> 4) * 8;

    f32x4 acc[4][4];
    #pragma unroll
    for (int m = 0; m < 4; ++m)
        #pragma unroll
        for (int n = 0; n < 4; ++n) {
            acc[m][n][0] = 0.f; acc[m][n][1] = 0.f;
            acc[m][n][2] = 0.f; acc[m][n][3] = 0.f;
        }

    const int off0 = tid * 16;
    for (int k0 = 0; k0 < K; k0 += 32) {
        #pragma unroll
        for (int c = 0; c < 2; ++c) {
            const int off = off0 + c * 4096;
            const int row = off >> 6;
            const int ke  = (off & 63) >> 1;
            const size_t ga = (size_t)(bm + row) * K + (k0 + ke);
            const size_t gb = (size_t)(bn + row) * K + (k0 + ke);
            gload16(Ah + ga,  (char*)As_h + off);
            gload16(Al + ga,  (char*)As_l + off);
            gload16(Wh + gb,  (char*)Bs_h + off);
            gload16(Wlo + gb, (char*)Bs_l + off);
        }
        __syncthreads();
        bf16x8 a_h[4], a_l[4], b_h[4], b_l[4];
        #pragma unroll
        for (int m = 0; m < 4; ++m) {
            const int r = wm * 64 + m * 16 + rsel;
            a_h[m] = *(const bf16x8*)&As_h[r][kh];
            a_l[m] = *(const bf16x8*)&As_l[r][kh];
        }
        #pragma unroll
        for (int n = 0; n < 4; ++n) {
            const int r = wn * 64 + n * 16 + rsel;
            b_h[n] = *(const bf16x8*)&Bs_h[r][kh];
            b_l[n] = *(const bf16x8*)&Bs_l[r][kh];
        }
        #pragma unroll
        for (int m = 0; m < 4; ++m)
            #pragma unroll
            for (int n = 0; n < 4; ++n) {
                acc[m][n] = __builtin_amdgcn_mfma_f32_16x16x32_bf16(a_h[m], b_h[n], acc[m][n], 0, 0, 0);
                acc[m][n] = __builtin_amdgcn_mfma_f32_16x16x32_bf16(a_h[m], b_l[n], acc[m][n], 0, 0, 0);
                acc[m][n] = __builtin_amdgcn_mfma_f32_16x16x32_bf16(a_l[m], b_h[n], acc[m][n], 0, 0, 0);
            }
        __syncthreads();
    }

    float bs[4], sc[4], sh[4];
    int cols[4];
    #pragma unroll
    for (int n = 0; n < 4; ++n) {
        const int col = bn + wn * 64 + n * 16 + rsel;
        cols[n] = col;
        bs[n] = bias[col];
        if (DO_BN) {
            const float s = g[col] * rsqrtf(rv[col] + 1e-5f);
            sc[n] = s;
            sh[n] = be[col] - rm[col] * s;
        } else {
            sc[n] = 0.f; sh[n] = 0.f;
        }
    }
    #pragma unroll
    for (int m = 0; m < 4; ++m) {
        #pragma unroll
        for (int r = 0; r < 4; ++r) {
            const int row = bm + wm * 64 + m * 16 + (lane >> 4) * 4 + r;
            #pragma unroll
            for (int n = 0; n < 4; ++n) {
                float v = acc[m][n][r] + bs[n];
                v = fmaxf(v, 0.f);
                if (DO_BN) v = v * sc[n] + sh[n];
                const ushort hb = f2bf(v);
                const ushort lb = f2bf(v - bf2f(hb));
                const size_t o = (size_t)row * Nout + cols[n];
                Oh[o] = hb;
                Ol[o] = lb;
            }
        }
    }
}

// ---------------- edge head: out[t] = (h[a]*h[b]) @ Wf + bf ----------------

__global__ __launch_bounds__(256) void k_edge(
    const ushort* __restrict__ hh, const ushort* __restrict__ hl,
    const int* __restrict__ ei, const int* __restrict__ tids,
    const float* __restrict__ Wf, const float* __restrict__ bf_,
    float* __restrict__ out, int Etr, int E) {
    __shared__ float wf[H_DIM * N_CLS];
    for (int i = threadIdx.x; i < H_DIM * N_CLS; i += 256) wf[i] = Wf[i];
    __syncthreads();
    const int wave = threadIdx.x >> 6, lane = threadIdx.x & 63;
    const int t = blockIdx.x * 4 + wave;
    if (t >= Etr) return;
    const int eid = tids[t];
    const size_t a = (size_t)ei[eid] * H_DIM;
    const size_t b = (size_t)ei[E + eid] * H_DIM;
    float acc[N_CLS] = {0.f, 0.f, 0.f, 0.f, 0.f, 0.f, 0.f};
    #pragma unroll
    for (int j = 0; j < 2; ++j) {
        const int k = j * 256 + lane * 4;
        ushort4 ah = *(const ushort4*)(hh + a + k);
        ushort4 al = *(const ushort4*)(hl + a + k);
        ushort4 bh = *(const ushort4*)(hh + b + k);
        ushort4 bl = *(const ushort4*)(hl + b + k);
        float va[4] = {bf2f(ah.x) + bf2f(al.x), bf2f(ah.y) + bf2f(al.y),
                       bf2f(ah.z) + bf2f(al.z), bf2f(ah.w) + bf2f(al.w)};
        float vb[4] = {bf2f(bh.x) + bf2f(bl.x), bf2f(bh.y) + bf2f(bl.y),
                       bf2f(bh.z) + bf2f(bl.z), bf2f(bh.w) + bf2f(bl.w)};
        #pragma unroll
        for (int q = 0; q < 4; ++q) {
            const float ep = va[q] * vb[q];
            #pragma unroll
            for (int c = 0; c < N_CLS; ++c) acc[c] = fmaf(ep, wf[(k + q) * N_CLS + c], acc[c]);
        }
    }
    #pragma unroll
    for (int o = 32; o; o >>= 1)
        #pragma unroll
        for (int c = 0; c < N_CLS; ++c) acc[c] += __shfl_xor(acc[c], o, 64);
    if (lane == 0) {
        #pragma unroll
        for (int c = 0; c < N_CLS; ++c) out[(size_t)t * N_CLS + c] = acc[c] + bf_[c];
    }
}

// ---------------- launch ----------------

extern "C" void kernel_launch(void* const* d_in, const int* in_sizes, int n_in,
                              void* d_out, int out_size, void* d_ws, size_t ws_size,
                              hipStream_t stream) {
    const float* x    = (const float*)d_in[0];
    const int*   ei   = (const int*)d_in[1];
    const int*   tids = (const int*)d_in[2];
    const float* eps1 = (const float*)d_in[3];
    const float* W1a  = (const float*)d_in[4];
    const float* b1a  = (const float*)d_in[5];
    const float* W1b  = (const float*)d_in[6];
    const float* b1b  = (const float*)d_in[7];
    const float* g1p  = (const float*)d_in[8];
    const float* be1  = (const float*)d_in[9];
    const float* rm1  = (const float*)d_in[10];
    const float* rv1  = (const float*)d_in[11];
    const float* eps2 = (const float*)d_in[12];
    const float* W2a  = (const float*)d_in[13];
    const float* b2a  = (const float*)d_in[14];
    const float* g2p  = (const float*)d_in[15];
    const float* be2  = (const float*)d_in[16];
    const float* rm2  = (const float*)d_in[17];
    const float* rv2  = (const float*)d_in[18];
    const float* Wl   = (const float*)d_in[19];
    const float* bl   = (const float*)d_in[20];
    const float* Wf   = (const float*)d_in[21];
    const float* bf   = (const float*)d_in[22];
    float* out = (float*)d_out;

    const int E   = in_sizes[1] / 2;
    const int Etr = in_sizes[2];

    char* ws = (char*)d_ws;
    size_t off = 0;
    auto alloc = [&](size_t bytes) -> char* {
        char* p = ws + off;
        off += (bytes + 255) & ~(size_t)255;
        return p;
    };
    int*    counts  = (int*)alloc((size_t)N_NODES * 4);
    int*    offsets = (int*)alloc((size_t)(N_NODES + 1) * 4);
    int*    cursor  = (int*)alloc((size_t)N_NODES * 4);
    int*    csr_src = (int*)alloc((size_t)E * 4);
    ushort* h0h = (ushort*)alloc((size_t)M_PAD * F_IN * 2);
    ushort* h0l = (ushort*)alloc((size_t)M_PAD * F_IN * 2);
    ushort* Ahh = (ushort*)alloc((size_t)M_PAD * H_DIM * 2);  // pair A
    ushort* Ahl = (ushort*)alloc((size_t)M_PAD * H_DIM * 2);
    ushort* Bhh = (ushort*)alloc((size_t)M_PAD * H_DIM * 2);  // pair B
    ushort* Bhl = (ushort*)alloc((size_t)M_PAD * H_DIM * 2);
    ushort* wt1a_h = (ushort*)alloc((size_t)H_DIM * F_IN * 2);
    ushort* wt1a_l = (ushort*)alloc((size_t)H_DIM * F_IN * 2);
    ushort* wt1b_h = (ushort*)alloc((size_t)H_DIM * H_DIM * 2);
    ushort* wt1b_l = (ushort*)alloc((size_t)H_DIM * H_DIM * 2);
    ushort* wt2a_h = (ushort*)alloc((size_t)H_DIM * H_DIM * 2);
    ushort* wt2a_l = (ushort*)alloc((size_t)H_DIM * H_DIM * 2);
    ushort* wtl_h  = (ushort*)alloc((size_t)H_DIM * H_DIM * 2);
    ushort* wtl_l  = (ushort*)alloc((size_t)H_DIM * H_DIM * 2);
    (void)ws_size; (void)n_in; (void)out_size;

    // CSR by dst
    k_zero_i32<<<(N_NODES + 255) / 256, 256, 0, stream>>>(counts, N_NODES);
    k_hist<<<(E + 255) / 256, 256, 0, stream>>>(ei, counts, E);
    k_scan<<<1, 1024, 0, stream>>>(counts, offsets, cursor, N_NODES, E);
    k_scatter<<<(E + 255) / 256, 256, 0, stream>>>(ei, cursor, csr_src, E);

    // weight hi/lo transposed splits
    k_wsplit<<<(H_DIM * F_IN + 255) / 256, 256, 0, stream>>>(W1a, wt1a_h, wt1a_l, F_IN, H_DIM);
    k_wsplit<<<(H_DIM * H_DIM + 255) / 256, 256, 0, stream>>>(W1b, wt1b_h, wt1b_l, H_DIM, H_DIM);
    k_wsplit<<<(H_DIM * H_DIM + 255) / 256, 256, 0, stream>>>(W2a, wt2a_h, wt2a_l, H_DIM, H_DIM);
    k_wsplit<<<(H_DIM * H_DIM + 255) / 256, 256, 0, stream>>>(Wl,  wtl_h,  wtl_l,  H_DIM, H_DIM);

    // h0 = (1+eps1)*x + agg(x)  -> pair (pad rows stay poison; row-contained)
    k_agg_f32<<<N_NODES, 128, 0, stream>>>(x, csr_src, offsets, eps1, h0h, h0l);

    dim3 gdim(M_PAD / 128, H_DIM / 128);
    // h1 = relu(h0 @ W1a + b1a)            -> pair A
    k_gemm_mfma<0><<<gdim, 256, 0, stream>>>(h0h, h0l, wt1a_h, wt1a_l, b1a,
                                             nullptr, nullptr, nullptr, nullptr,
                                             Ahh, Ahl, F_IN, H_DIM);
    // h2 = bn1(relu(h1 @ W1b + b1b))       -> pair B
    k_gemm_mfma<1><<<gdim, 256, 0, stream>>>(Ahh, Ahl, wt1b_h, wt1b_l, b1b,
                                             g1p, be1, rm1, rv1,
                                             Bhh, Bhl, H_DIM, H_DIM);
    // h3 = (1+eps2)*h2 + agg(h2)           -> pair A
    k_agg_pair<<<N_NODES, 128, 0, stream>>>(Bhh, Bhl, csr_src, offsets, eps2, Ahh, Ahl);
    // h4 = bn2(relu(h3 @ W2a + b2a))       -> pair B
    k_gemm_mfma<1><<<gdim, 256, 0, stream>>>(Ahh, Ahl, wt2a_h, wt2a_l, b2a,
                                             g2p, be2, rm2, rv2,
                                             Bhh, Bhl, H_DIM, H_DIM);
    // h5 = relu(h4 @ Wl + bl)              -> pair A
    k_gemm_mfma<0><<<gdim, 256, 0, stream>>>(Bhh, Bhl, wtl_h, wtl_l, bl,
                                             nullptr, nullptr, nullptr, nullptr,
                                             Ahh, Ahl, H_DIM, H_DIM);
    // edge head
    k_edge<<<(Etr + 3) / 4, 256, 0, stream>>>(Ahh, Ahl, ei, tids, Wf, bf, out, Etr, E);
}

// Round 8
// 346.374 us; speedup vs baseline: 1.6969x; 1.0789x over previous
//
#include <hip/hip_runtime.h>
#include <hip/hip_bf16.h>

#define N_NODES 10000
#define M_PAD   10112   // 158*64
#define F_IN    128
#define H_DIM   512
#define N_CLS   7

typedef __bf16  bf16x8  __attribute__((ext_vector_type(8)));
typedef float   f32x4   __attribute__((ext_vector_type(4)));
typedef ushort  ushort8 __attribute__((ext_vector_type(8)));

__device__ __forceinline__ ushort f2bf(float f) {
    union { float f; unsigned u; } x; x.f = f;
    unsigned r = x.u + 0x7fffu + ((x.u >> 16) & 1u);
    return (ushort)(r >> 16);
}
__device__ __forceinline__ float bf2f(ushort h) {
    union { unsigned u; float f; } x; x.u = ((unsigned)h) << 16;
    return x.f;
}

__device__ __forceinline__ void gload16(const void* g, void* l) {
    __builtin_amdgcn_global_load_lds(
        (const __attribute__((address_space(1))) void*)g,
        (__attribute__((address_space(3))) void*)l, 16, 0, 0);
}

// ---------------- CSR build ----------------

__global__ void k_zero_i32(int* __restrict__ p, int n) {
    int i = blockIdx.x * blockDim.x + threadIdx.x;
    if (i < n) p[i] = 0;
}

__global__ void k_hist(const int* __restrict__ ei, int* __restrict__ counts, int E) {
    int e = blockIdx.x * blockDim.x + threadIdx.x;
    if (e < E) atomicAdd(&counts[ei[E + e]], 1);  // dst
}

__global__ __launch_bounds__(1024) void k_scan(const int* __restrict__ counts,
                                               int* __restrict__ offsets,
                                               int* __restrict__ cursor,
                                               int N, int E) {
    __shared__ int sm[1024];
    int t = threadIdx.x;
    int base = t * 10;
    int loc[10];
    int s = 0;
    #pragma unroll
    for (int i = 0; i < 10; ++i) {
        int idx = base + i;
        int c = (idx < N) ? counts[idx] : 0;
        loc[i] = s;
        s += c;
    }
    sm[t] = s;
    __syncthreads();
    for (int off = 1; off < 1024; off <<= 1) {
        int v = (t >= off) ? sm[t - off] : 0;
        __syncthreads();
        sm[t] += v;
        __syncthreads();
    }
    int excl = sm[t] - s;
    #pragma unroll
    for (int i = 0; i < 10; ++i) {
        int idx = base + i;
        if (idx < N) {
            int o = excl + loc[i];
            offsets[idx] = o;
            cursor[idx] = o;
        }
    }
    if (t == 0) offsets[N] = E;
}

__global__ void k_scatter(const int* __restrict__ ei, int* __restrict__ cursor,
                          int* __restrict__ csr_src, int E) {
    int e = blockIdx.x * blockDim.x + threadIdx.x;
    if (e < E) {
        int d = ei[E + e];
        int pos = atomicAdd(&cursor[d], 1);
        csr_src[pos] = ei[e];
    }
}

// ---------------- weight split: W (K x N fp32) -> Wt_hi/Wt_lo (N x K bf16) ----------------

__global__ void k_wsplit(const float* __restrict__ W, ushort* __restrict__ Th,
                         ushort* __restrict__ Tl, int K, int N) {
    int idx = blockIdx.x * blockDim.x + threadIdx.x;
    if (idx >= K * N) return;
    int n = idx / K, k = idx % K;
    float w = W[(size_t)k * N + n];
    ushort hb = f2bf(w);
    Th[idx] = hb;
    Tl[idx] = f2bf(w - bf2f(hb));
}

// ---------------- GIN agg, fp32 input (F=128): out pair = (1+eps)*X + sum nbrs ----------------

__global__ __launch_bounds__(128) void k_agg_f32(
    const float* __restrict__ X, const int* __restrict__ csr,
    const int* __restrict__ offs, const float* __restrict__ eps,
    ushort* __restrict__ Oh, ushort* __restrict__ Ol) {
    const int n = blockIdx.x, f = threadIdx.x;
    const int s0 = offs[n], s1 = offs[n + 1];
    float s = 0.f;
    for (int i = s0; i < s1; ++i) s += X[(size_t)csr[i] * F_IN + f];
    const float v = (1.f + eps[0]) * X[(size_t)n * F_IN + f] + s;
    const ushort hb = f2bf(v);
    const size_t o = (size_t)n * F_IN + f;
    Oh[o] = hb;
    Ol[o] = f2bf(v - bf2f(hb));
}

// ---------------- GIN agg, pair input (F=512), 128 thr x 4 cols ----------------

__global__ __launch_bounds__(128) void k_agg_pair(
    const ushort* __restrict__ Xh, const ushort* __restrict__ Xl,
    const int* __restrict__ csr, const int* __restrict__ offs,
    const float* __restrict__ eps,
    ushort* __restrict__ Oh, ushort* __restrict__ Ol) {
    const int n = blockIdx.x;
    const size_t c0 = (size_t)threadIdx.x * 4;
    const int s0 = offs[n], s1 = offs[n + 1];
    float a0 = 0.f, a1 = 0.f, a2 = 0.f, a3 = 0.f;
    for (int i = s0; i < s1; ++i) {
        const size_t b = (size_t)csr[i] * H_DIM + c0;
        ushort4 h = *(const ushort4*)(Xh + b);
        ushort4 l = *(const ushort4*)(Xl + b);
        a0 += bf2f(h.x) + bf2f(l.x);
        a1 += bf2f(h.y) + bf2f(l.y);
        a2 += bf2f(h.z) + bf2f(l.z);
        a3 += bf2f(h.w) + bf2f(l.w);
    }
    const size_t b = (size_t)n * H_DIM + c0;
    ushort4 h = *(const ushort4*)(Xh + b);
    ushort4 l = *(const ushort4*)(Xl + b);
    const float e = 1.f + eps[0];
    float v0 = e * (bf2f(h.x) + bf2f(l.x)) + a0;
    float v1 = e * (bf2f(h.y) + bf2f(l.y)) + a1;
    float v2 = e * (bf2f(h.z) + bf2f(l.z)) + a2;
    float v3 = e * (bf2f(h.w) + bf2f(l.w)) + a3;
    ushort4 oh, ol;
    oh.x = f2bf(v0); ol.x = f2bf(v0 - bf2f(oh.x));
    oh.y = f2bf(v1); ol.y = f2bf(v1 - bf2f(oh.y));
    oh.z = f2bf(v2); ol.z = f2bf(v2 - bf2f(oh.z));
    oh.w = f2bf(v3); ol.w = f2bf(v3 - bf2f(oh.w));
    *(ushort4*)(Oh + b) = oh;
    *(ushort4*)(Ol + b) = ol;
}

// ---------------- split-bf16 MFMA GEMM ----------------
// C = ep(A @ W + bias); A as hi/lo pair (M x K), W as hi/lo pair transposed [N][K].
// 64x128 tile (BM=64 for grid occupancy: 158x4 = 632 blocks on 256 CUs),
// BK=32, 4 waves 2x2 (32x64 each), mfma_f32_16x16x32_bf16.
// 3 MFMA terms per frag-pair: hi*hi + hi*lo + lo*hi  (drop lo*lo ~2^-16).
// ep: relu, then optional BN: v*s + (be - rm*s), s = g*rsqrt(rv+1e-5).
// Output written as hi/lo bf16 pair.

template <int DO_BN>
__global__ __launch_bounds__(256) void k_gemm_mfma(
    const ushort* __restrict__ Ah, const ushort* __restrict__ Al,
    const ushort* __restrict__ Wh, const ushort* __restrict__ Wlo,
    const float* __restrict__ bias,
    const float* __restrict__ g, const float* __restrict__ be,
    const float* __restrict__ rm, const float* __restrict__ rv,
    ushort* __restrict__ Oh, ushort* __restrict__ Ol,
    int K, int Nout) {
    __shared__ __align__(16) ushort As_h[64][32];
    __shared__ __align__(16) ushort As_l[64][32];
    __shared__ __align__(16) ushort Bs_h[128][32];
    __shared__ __align__(16) ushort Bs_l[128][32];

    const int tid  = threadIdx.x;
    const int lane = tid & 63;
    const int wid  = tid >> 6;
    const int wm   = wid >> 1, wn = wid & 1;   // 2x2 waves, wave tile 32x64
    const int bm = blockIdx.x * 64, bn = blockIdx.y * 128;
    const int rsel = lane & 15;
    const int kh   = (lane >> 4) * 8;

    f32x4 acc[2][4];
    #pragma unroll
    for (int m = 0; m < 2; ++m)
        #pragma unroll
        for (int n = 0; n < 4; ++n) {
            acc[m][n][0] = 0.f; acc[m][n][1] = 0.f;
            acc[m][n][2] = 0.f; acc[m][n][3] = 0.f;
        }

    for (int k0 = 0; k0 < K; k0 += 32) {
        // A tiles: 64x32 ushorts = 4KB each -> 1 gload16/thread/array
        {
            const int off = tid * 16;          // 0..4080
            const int row = off >> 6;          // 0..63
            const int ke  = (off & 63) >> 1;
            const size_t ga = (size_t)(bm + row) * K + (k0 + ke);
            gload16(Ah + ga, (char*)As_h + off);
            gload16(Al + ga, (char*)As_l + off);
        }
        // B tiles: 128x32 ushorts = 8KB each -> 2 gload16/thread/array
        #pragma unroll
        for (int c = 0; c < 2; ++c) {
            const int off = tid * 16 + c * 4096;
            const int row = off >> 6;          // 0..127
            const int ke  = (off & 63) >> 1;
            const size_t gb = (size_t)(bn + row) * K + (k0 + ke);
            gload16(Wh + gb,  (char*)Bs_h + off);
            gload16(Wlo + gb, (char*)Bs_l + off);
        }
        __syncthreads();
        bf16x8 a_h[2], a_l[2], b_h[4], b_l[4];
        #pragma unroll
        for (int m = 0; m < 2; ++m) {
            const int r = wm * 32 + m * 16 + rsel;
            a_h[m] = *(const bf16x8*)&As_h[r][kh];
            a_l[m] = *(const bf16x8*)&As_l[r][kh];
        }
        #pragma unroll
        for (int n = 0; n < 4; ++n) {
            const int r = wn * 64 + n * 16 + rsel;
            b_h[n] = *(const bf16x8*)&Bs_h[r][kh];
            b_l[n] = *(const bf16x8*)&Bs_l[r][kh];
        }
        #pragma unroll
        for (int m = 0; m < 2; ++m)
            #pragma unroll
            for (int n = 0; n < 4; ++n) {
                acc[m][n] = __builtin_amdgcn_mfma_f32_16x16x32_bf16(a_h[m], b_h[n], acc[m][n], 0, 0, 0);
                acc[m][n] = __builtin_amdgcn_mfma_f32_16x16x32_bf16(a_h[m], b_l[n], acc[m][n], 0, 0, 0);
                acc[m][n] = __builtin_amdgcn_mfma_f32_16x16x32_bf16(a_l[m], b_h[n], acc[m][n], 0, 0, 0);
            }
        __syncthreads();
    }

    float bs[4], sc[4], sh[4];
    int cols[4];
    #pragma unroll
    for (int n = 0; n < 4; ++n) {
        const int col = bn + wn * 64 + n * 16 + rsel;
        cols[n] = col;
        bs[n] = bias[col];
        if (DO_BN) {
            const float s = g[col] * rsqrtf(rv[col] + 1e-5f);
            sc[n] = s;
            sh[n] = be[col] - rm[col] * s;
        } else {
            sc[n] = 0.f; sh[n] = 0.f;
        }
    }
    #pragma unroll
    for (int m = 0; m < 2; ++m) {
        #pragma unroll
        for (int r = 0; r < 4; ++r) {
            const int row = bm + wm * 32 + m * 16 + (lane >> 4) * 4 + r;
            #pragma unroll
            for (int n = 0; n < 4; ++n) {
                float v = acc[m][n][r] + bs[n];
                v = fmaxf(v, 0.f);
                if (DO_BN) v = v * sc[n] + sh[n];
                const ushort hb = f2bf(v);
                const ushort lb = f2bf(v - bf2f(hb));
                const size_t o = (size_t)row * Nout + cols[n];
                Oh[o] = hb;
                Ol[o] = lb;
            }
        }
    }
}

// ---------------- edge head: out[t] = (h[a]*h[b]) @ Wf + bf ----------------
// Wf held in registers (lane owns k-rows lane*8..lane*8+7 -> 56 VGPR, no LDS,
// no bank conflicts). Grid-stride: each wave processes ~Etr/(blocks*4) edges,
// independent iterations give the scheduler gather-latency overlap.

__global__ __launch_bounds__(256) void k_edge(
    const ushort* __restrict__ hh, const ushort* __restrict__ hl,
    const int* __restrict__ ei, const int* __restrict__ tids,
    const float* __restrict__ Wf, const float* __restrict__ bf_,
    float* __restrict__ out, int Etr, int E) {
    const int lane = threadIdx.x & 63;
    const int wv   = threadIdx.x >> 6;
    // per-lane Wf slice: rows lane*8 .. lane*8+7, 7 classes each
    float wfr[8][N_CLS];
    #pragma unroll
    for (int r = 0; r < 8; ++r)
        #pragma unroll
        for (int c = 0; c < N_CLS; ++c)
            wfr[r][c] = Wf[(lane * 8 + r) * N_CLS + c];
    float bfr[N_CLS];
    #pragma unroll
    for (int c = 0; c < N_CLS; ++c) bfr[c] = bf_[c];

    const int wid  = blockIdx.x * 4 + wv;
    const int step = gridDim.x * 4;
    for (int t = wid; t < Etr; t += step) {
        const int eid = tids[t];
        const size_t a = (size_t)ei[eid] * H_DIM + lane * 8;
        const size_t b = (size_t)ei[E + eid] * H_DIM + lane * 8;
        const ushort8 ah = *(const ushort8*)(hh + a);
        const ushort8 al = *(const ushort8*)(hl + a);
        const ushort8 bh = *(const ushort8*)(hh + b);
        const ushort8 bl = *(const ushort8*)(hl + b);
        float acc[N_CLS] = {0.f, 0.f, 0.f, 0.f, 0.f, 0.f, 0.f};
        #pragma unroll
        for (int r = 0; r < 8; ++r) {
            const float va = bf2f(ah[r]) + bf2f(al[r]);
            const float vb = bf2f(bh[r]) + bf2f(bl[r]);
            const float e = va * vb;
            #pragma unroll
            for (int c = 0; c < N_CLS; ++c) acc[c] = fmaf(e, wfr[r][c], acc[c]);
        }
        #pragma unroll
        for (int o = 32; o; o >>= 1)
            #pragma unroll
            for (int c = 0; c < N_CLS; ++c) acc[c] += __shfl_xor(acc[c], o, 64);
        if (lane == 0) {
            #pragma unroll
            for (int c = 0; c < N_CLS; ++c) out[(size_t)t * N_CLS + c] = acc[c] + bfr[c];
        }
    }
}

// ---------------- launch ----------------

extern "C" void kernel_launch(void* const* d_in, const int* in_sizes, int n_in,
                              void* d_out, int out_size, void* d_ws, size_t ws_size,
                              hipStream_t stream) {
    const float* x    = (const float*)d_in[0];
    const int*   ei   = (const int*)d_in[1];
    const int*   tids = (const int*)d_in[2];
    const float* eps1 = (const float*)d_in[3];
    const float* W1a  = (const float*)d_in[4];
    const float* b1a  = (const float*)d_in[5];
    const float* W1b  = (const float*)d_in[6];
    const float* b1b  = (const float*)d_in[7];
    const float* g1p  = (const float*)d_in[8];
    const float* be1  = (const float*)d_in[9];
    const float* rm1  = (const float*)d_in[10];
    const float* rv1  = (const float*)d_in[11];
    const float* eps2 = (const float*)d_in[12];
    const float* W2a  = (const float*)d_in[13];
    const float* b2a  = (const float*)d_in[14];
    const float* g2p  = (const float*)d_in[15];
    const float* be2  = (const float*)d_in[16];
    const float* rm2  = (const float*)d_in[17];
    const float* rv2  = (const float*)d_in[18];
    const float* Wl   = (const float*)d_in[19];
    const float* bl   = (const float*)d_in[20];
    const float* Wf   = (const float*)d_in[21];
    const float* bf   = (const float*)d_in[22];
    float* out = (float*)d_out;

    const int E   = in_sizes[1] / 2;
    const int Etr = in_sizes[2];

    char* ws = (char*)d_ws;
    size_t off = 0;
    auto alloc = [&](size_t bytes) -> char* {
        char* p = ws + off;
        off += (bytes + 255) & ~(size_t)255;
        return p;
    };
    int*    counts  = (int*)alloc((size_t)N_NODES * 4);
    int*    offsets = (int*)alloc((size_t)(N_NODES + 1) * 4);
    int*    cursor  = (int*)alloc((size_t)N_NODES * 4);
    int*    csr_src = (int*)alloc((size_t)E * 4);
    ushort* h0h = (ushort*)alloc((size_t)M_PAD * F_IN * 2);
    ushort* h0l = (ushort*)alloc((size_t)M_PAD * F_IN * 2);
    ushort* Ahh = (ushort*)alloc((size_t)M_PAD * H_DIM * 2);  // pair A
    ushort* Ahl = (ushort*)alloc((size_t)M_PAD * H_DIM * 2);
    ushort* Bhh = (ushort*)alloc((size_t)M_PAD * H_DIM * 2);  // pair B
    ushort* Bhl = (ushort*)alloc((size_t)M_PAD * H_DIM * 2);
    ushort* wt1a_h = (ushort*)alloc((size_t)H_DIM * F_IN * 2);
    ushort* wt1a_l = (ushort*)alloc((size_t)H_DIM * F_IN * 2);
    ushort* wt1b_h = (ushort*)alloc((size_t)H_DIM * H_DIM * 2);
    ushort* wt1b_l = (ushort*)alloc((size_t)H_DIM * H_DIM * 2);
    ushort* wt2a_h = (ushort*)alloc((size_t)H_DIM * H_DIM * 2);
    ushort* wt2a_l = (ushort*)alloc((size_t)H_DIM * H_DIM * 2);
    ushort* wtl_h  = (ushort*)alloc((size_t)H_DIM * H_DIM * 2);
    ushort* wtl_l  = (ushort*)alloc((size_t)H_DIM * H_DIM * 2);
    (void)ws_size; (void)n_in; (void)out_size;

    // CSR by dst
    k_zero_i32<<<(N_NODES + 255) / 256, 256, 0, stream>>>(counts, N_NODES);
    k_hist<<<(E + 255) / 256, 256, 0, stream>>>(ei, counts, E);
    k_scan<<<1, 1024, 0, stream>>>(counts, offsets, cursor, N_NODES, E);
    k_scatter<<<(E + 255) / 256, 256, 0, stream>>>(ei, cursor, csr_src, E);

    // weight hi/lo transposed splits
    k_wsplit<<<(H_DIM * F_IN + 255) / 256, 256, 0, stream>>>(W1a, wt1a_h, wt1a_l, F_IN, H_DIM);
    k_wsplit<<<(H_DIM * H_DIM + 255) / 256, 256, 0, stream>>>(W1b, wt1b_h, wt1b_l, H_DIM, H_DIM);
    k_wsplit<<<(H_DIM * H_DIM + 255) / 256, 256, 0, stream>>>(W2a, wt2a_h, wt2a_l, H_DIM, H_DIM);
    k_wsplit<<<(H_DIM * H_DIM + 255) / 256, 256, 0, stream>>>(Wl,  wtl_h,  wtl_l,  H_DIM, H_DIM);

    // h0 = (1+eps1)*x + agg(x)  -> pair (pad rows stay poison; row-contained)
    k_agg_f32<<<N_NODES, 128, 0, stream>>>(x, csr_src, offsets, eps1, h0h, h0l);

    dim3 gdim(M_PAD / 64, H_DIM / 128);   // 158 x 4 = 632 blocks
    // h1 = relu(h0 @ W1a + b1a)            -> pair A
    k_gemm_mfma<0><<<gdim, 256, 0, stream>>>(h0h, h0l, wt1a_h, wt1a_l, b1a,
                                             nullptr, nullptr, nullptr, nullptr,
                                             Ahh, Ahl, F_IN, H_DIM);
    // h2 = bn1(relu(h1 @ W1b + b1b))       -> pair B
    k_gemm_mfma<1><<<gdim, 256, 0, stream>>>(Ahh, Ahl, wt1b_h, wt1b_l, b1b,
                                             g1p, be1, rm1, rv1,
                                             Bhh, Bhl, H_DIM, H_DIM);
    // h3 = (1+eps2)*h2 + agg(h2)           -> pair A
    k_agg_pair<<<N_NODES, 128, 0, stream>>>(Bhh, Bhl, csr_src, offsets, eps2, Ahh, Ahl);
    // h4 = bn2(relu(h3 @ W2a + b2a))       -> pair B
    k_gemm_mfma<1><<<gdim, 256, 0, stream>>>(Ahh, Ahl, wt2a_h, wt2a_l, b2a,
                                             g2p, be2, rm2, rv2,
                                             Bhh, Bhl, H_DIM, H_DIM);
    // h5 = relu(h4 @ Wl + bl)              -> pair A
    k_gemm_mfma<0><<<gdim, 256, 0, stream>>>(Bhh, Bhl, wtl_h, wtl_l, bl,
                                             nullptr, nullptr, nullptr, nullptr,
                                             Ahh, Ahl, H_DIM, H_DIM);
    // edge head (grid-stride, wf-in-registers)
    k_edge<<<2048, 256, 0, stream>>>(Ahh, Ahl, ei, tids, Wf, bf, out, Etr, E);
}

// Round 9
// 337.483 us; speedup vs baseline: 1.7417x; 1.0263x over previous
//
#include <hip/hip_runtime.h>
#include <hip/hip_bf16.h>

#define N_NODES 10000
#define M_PAD   10112   // 158*64
#define F_IN    128
#define H_DIM   512
#define N_CLS   7

typedef __bf16  bf16x8  __attribute__((ext_vector_type(8)));
typedef float   f32x4   __attribute__((ext_vector_type(4)));
typedef ushort  ushort8 __attribute__((ext_vector_type(8)));

__device__ __forceinline__ ushort f2bf(float f) {
    union { float f; unsigned u; } x; x.f = f;
    unsigned r = x.u + 0x7fffu + ((x.u >> 16) & 1u);
    return (ushort)(r >> 16);
}
__device__ __forceinline__ float bf2f(ushort h) {
    union { unsigned u; float f; } x; x.u = ((unsigned)h) << 16;
    return x.f;
}

__device__ __forceinline__ void gload16(const void* g, void* l) {
    __builtin_amdgcn_global_load_lds(
        (const __attribute__((address_space(1))) void*)g,
        (__attribute__((address_space(3))) void*)l, 16, 0, 0);
}

// ---------------- CSR build ----------------

__global__ void k_zero_i32(int* __restrict__ p, int n) {
    int i = blockIdx.x * blockDim.x + threadIdx.x;
    if (i < n) p[i] = 0;
}

__global__ void k_hist(const int* __restrict__ ei, int* __restrict__ counts, int E) {
    int e = blockIdx.x * blockDim.x + threadIdx.x;
    if (e < E) atomicAdd(&counts[ei[E + e]], 1);  // dst
}

__global__ __launch_bounds__(1024) void k_scan(const int* __restrict__ counts,
                                               int* __restrict__ offsets,
                                               int* __restrict__ cursor,
                                               int N, int E) {
    __shared__ int sm[1024];
    int t = threadIdx.x;
    int base = t * 10;
    int loc[10];
    int s = 0;
    #pragma unroll
    for (int i = 0; i < 10; ++i) {
        int idx = base + i;
        int c = (idx < N) ? counts[idx] : 0;
        loc[i] = s;
        s += c;
    }
    sm[t] = s;
    __syncthreads();
    for (int off = 1; off < 1024; off <<= 1) {
        int v = (t >= off) ? sm[t - off] : 0;
        __syncthreads();
        sm[t] += v;
        __syncthreads();
    }
    int excl = sm[t] - s;
    #pragma unroll
    for (int i = 0; i < 10; ++i) {
        int idx = base + i;
        if (idx < N) {
            int o = excl + loc[i];
            offsets[idx] = o;
            cursor[idx] = o;
        }
    }
    if (t == 0) offsets[N] = E;
}

__global__ void k_scatter(const int* __restrict__ ei, int* __restrict__ cursor,
                          int* __restrict__ csr_src, int E) {
    int e = blockIdx.x * blockDim.x + threadIdx.x;
    if (e < E) {
        int d = ei[E + e];
        int pos = atomicAdd(&cursor[d], 1);
        csr_src[pos] = ei[e];
    }
}

// ---------------- weight split: W (K x N fp32) -> Wt_hi/Wt_lo (N x K bf16) ----------------

__global__ void k_wsplit(const float* __restrict__ W, ushort* __restrict__ Th,
                         ushort* __restrict__ Tl, int K, int N) {
    int idx = blockIdx.x * blockDim.x + threadIdx.x;
    if (idx >= K * N) return;
    int n = idx / K, k = idx % K;
    float w = W[(size_t)k * N + n];
    ushort hb = f2bf(w);
    Th[idx] = hb;
    Tl[idx] = f2bf(w - bf2f(hb));
}

// ---------------- GIN agg, fp32 input (F=128): wave per node, float2/lane ----------------

__global__ __launch_bounds__(256) void k_agg_f32(
    const float* __restrict__ X, const int* __restrict__ csr,
    const int* __restrict__ offs, const float* __restrict__ eps,
    ushort* __restrict__ Oh, ushort* __restrict__ Ol) {
    const int wv = threadIdx.x >> 6, lane = threadIdx.x & 63;
    const int n = blockIdx.x * 4 + wv;
    if (n >= N_NODES) return;
    const int c0 = lane * 2;
    const int s0 = offs[n], s1 = offs[n + 1];
    float a0 = 0.f, a1 = 0.f;
    int i = s0;
    for (; i + 1 < s1; i += 2) {
        const float2 v0 = *(const float2*)(X + (size_t)csr[i] * F_IN + c0);
        const float2 v1 = *(const float2*)(X + (size_t)csr[i + 1] * F_IN + c0);
        a0 += v0.x + v1.x;
        a1 += v0.y + v1.y;
    }
    if (i < s1) {
        const float2 v = *(const float2*)(X + (size_t)csr[i] * F_IN + c0);
        a0 += v.x; a1 += v.y;
    }
    const float2 sv = *(const float2*)(X + (size_t)n * F_IN + c0);
    const float e = 1.f + eps[0];
    const float v0 = e * sv.x + a0;
    const float v1 = e * sv.y + a1;
    ushort2 oh, ol;
    oh.x = f2bf(v0); ol.x = f2bf(v0 - bf2f(oh.x));
    oh.y = f2bf(v1); ol.y = f2bf(v1 - bf2f(oh.y));
    const size_t o = (size_t)n * F_IN + c0;
    *(ushort2*)(Oh + o) = oh;
    *(ushort2*)(Ol + o) = ol;
}

// ---------------- GIN agg, pair input (F=512): wave per node, ushort8/lane ----------------
// 4 nodes per 256-thr block (one wave each, no syncthreads); 16B loads halve
// the load-instruction count; x2 neighbor unroll doubles rows in flight.

__global__ __launch_bounds__(256) void k_agg_pair(
    const ushort* __restrict__ Xh, const ushort* __restrict__ Xl,
    const int* __restrict__ csr, const int* __restrict__ offs,
    const float* __restrict__ eps,
    ushort* __restrict__ Oh, ushort* __restrict__ Ol) {
    const int wv = threadIdx.x >> 6, lane = threadIdx.x & 63;
    const int n = blockIdx.x * 4 + wv;
    if (n >= N_NODES) return;
    const int c0 = lane * 8;
    const int s0 = offs[n], s1 = offs[n + 1];
    float acc[8] = {0.f, 0.f, 0.f, 0.f, 0.f, 0.f, 0.f, 0.f};
    int i = s0;
    for (; i + 1 < s1; i += 2) {
        const size_t b0 = (size_t)csr[i] * H_DIM + c0;
        const size_t b1 = (size_t)csr[i + 1] * H_DIM + c0;
        const ushort8 h0 = *(const ushort8*)(Xh + b0);
        const ushort8 l0 = *(const ushort8*)(Xl + b0);
        const ushort8 h1 = *(const ushort8*)(Xh + b1);
        const ushort8 l1 = *(const ushort8*)(Xl + b1);
        #pragma unroll
        for (int r = 0; r < 8; ++r)
            acc[r] += (bf2f(h0[r]) + bf2f(l0[r])) + (bf2f(h1[r]) + bf2f(l1[r]));
    }
    if (i < s1) {
        const size_t b = (size_t)csr[i] * H_DIM + c0;
        const ushort8 h = *(const ushort8*)(Xh + b);
        const ushort8 l = *(const ushort8*)(Xl + b);
        #pragma unroll
        for (int r = 0; r < 8; ++r) acc[r] += bf2f(h[r]) + bf2f(l[r]);
    }
    const size_t b = (size_t)n * H_DIM + c0;
    const ushort8 h = *(const ushort8*)(Xh + b);
    const ushort8 l = *(const ushort8*)(Xl + b);
    const float e = 1.f + eps[0];
    ushort8 oh, ol;
    #pragma unroll
    for (int r = 0; r < 8; ++r) {
        const float v = e * (bf2f(h[r]) + bf2f(l[r])) + acc[r];
        oh[r] = f2bf(v);
        ol[r] = f2bf(v - bf2f(oh[r]));
    }
    *(ushort8*)(Oh + b) = oh;
    *(ushort8*)(Ol + b) = ol;
}

// ---------------- split-bf16 MFMA GEMM ----------------
// C = ep(A @ W + bias); A as hi/lo pair (M x K), W as hi/lo pair transposed [N][K].
// 64x128 tile (grid 158x4 = 632 blocks), BK=32, 4 waves 2x2 (32x64 each),
// mfma_f32_16x16x32_bf16; 3 MFMA terms: hi*hi + hi*lo + lo*hi.
// ep: relu, then optional BN. Output written as hi/lo bf16 pair.

template <int DO_BN>
__global__ __launch_bounds__(256) void k_gemm_mfma(
    const ushort* __restrict__ Ah, const ushort* __restrict__ Al,
    const ushort* __restrict__ Wh, const ushort* __restrict__ Wlo,
    const float* __restrict__ bias,
    const float* __restrict__ g, const float* __restrict__ be,
    const float* __restrict__ rm, const float* __restrict__ rv,
    ushort* __restrict__ Oh, ushort* __restrict__ Ol,
    int K, int Nout) {
    __shared__ __align__(16) ushort As_h[64][32];
    __shared__ __align__(16) ushort As_l[64][32];
    __shared__ __align__(16) ushort Bs_h[128][32];
    __shared__ __align__(16) ushort Bs_l[128][32];

    const int tid  = threadIdx.x;
    const int lane = tid & 63;
    const int wid  = tid >> 6;
    const int wm   = wid >> 1, wn = wid & 1;   // 2x2 waves, wave tile 32x64
    const int bm = blockIdx.x * 64, bn = blockIdx.y * 128;
    const int rsel = lane & 15;
    const int kh   = (lane >> 4) * 8;

    f32x4 acc[2][4];
    #pragma unroll
    for (int m = 0; m < 2; ++m)
        #pragma unroll
        for (int n = 0; n < 4; ++n) {
            acc[m][n][0] = 0.f; acc[m][n][1] = 0.f;
            acc[m][n][2] = 0.f; acc[m][n][3] = 0.f;
        }

    for (int k0 = 0; k0 < K; k0 += 32) {
        {
            const int off = tid * 16;          // A: 64x32 = 4KB/plane
            const int row = off >> 6;
            const int ke  = (off & 63) >> 1;
            const size_t ga = (size_t)(bm + row) * K + (k0 + ke);
            gload16(Ah + ga, (char*)As_h + off);
            gload16(Al + ga, (char*)As_l + off);
        }
        #pragma unroll
        for (int c = 0; c < 2; ++c) {
            const int off = tid * 16 + c * 4096;  // B: 128x32 = 8KB/plane
            const int row = off >> 6;
            const int ke  = (off & 63) >> 1;
            const size_t gb = (size_t)(bn + row) * K + (k0 + ke);
            gload16(Wh + gb,  (char*)Bs_h + off);
            gload16(Wlo + gb, (char*)Bs_l + off);
        }
        __syncthreads();
        bf16x8 a_h[2], a_l[2], b_h[4], b_l[4];
        #pragma unroll
        for (int m = 0; m < 2; ++m) {
            const int r = wm * 32 + m * 16 + rsel;
            a_h[m] = *(const bf16x8*)&As_h[r][kh];
            a_l[m] = *(const bf16x8*)&As_l[r][kh];
        }
        #pragma unroll
        for (int n = 0; n < 4; ++n) {
            const int r = wn * 64 + n * 16 + rsel;
            b_h[n] = *(const bf16x8*)&Bs_h[r][kh];
            b_l[n] = *(const bf16x8*)&Bs_l[r][kh];
        }
        #pragma unroll
        for (int m = 0; m < 2; ++m)
            #pragma unroll
            for (int n = 0; n < 4; ++n) {
                acc[m][n] = __builtin_amdgcn_mfma_f32_16x16x32_bf16(a_h[m], b_h[n], acc[m][n], 0, 0, 0);
                acc[m][n] = __builtin_amdgcn_mfma_f32_16x16x32_bf16(a_h[m], b_l[n], acc[m][n], 0, 0, 0);
                acc[m][n] = __builtin_amdgcn_mfma_f32_16x16x32_bf16(a_l[m], b_h[n], acc[m][n], 0, 0, 0);
            }
        __syncthreads();
    }

    float bs[4], sc[4], sh[4];
    int cols[4];
    #pragma unroll
    for (int n = 0; n < 4; ++n) {
        const int col = bn + wn * 64 + n * 16 + rsel;
        cols[n] = col;
        bs[n] = bias[col];
        if (DO_BN) {
            const float s = g[col] * rsqrtf(rv[col] + 1e-5f);
            sc[n] = s;
            sh[n] = be[col] - rm[col] * s;
        } else {
            sc[n] = 0.f; sh[n] = 0.f;
        }
    }
    #pragma unroll
    for (int m = 0; m < 2; ++m) {
        #pragma unroll
        for (int r = 0; r < 4; ++r) {
            const int row = bm + wm * 32 + m * 16 + (lane >> 4) * 4 + r;
            #pragma unroll
            for (int n = 0; n < 4; ++n) {
                float v = acc[m][n][r] + bs[n];
                v = fmaxf(v, 0.f);
                if (DO_BN) v = v * sc[n] + sh[n];
                const ushort hb = f2bf(v);
                const ushort lb = f2bf(v - bf2f(hb));
                const size_t o = (size_t)row * Nout + cols[n];
                Oh[o] = hb;
                Ol[o] = lb;
            }
        }
    }
}

// ---------------- edge head: out[t] = (h[a]*h[b]) @ Wf + bf ----------------
// Wf in registers (lane owns k-rows lane*8..lane*8+7); grid-stride waves.

__global__ __launch_bounds__(256) void k_edge(
    const ushort* __restrict__ hh, const ushort* __restrict__ hl,
    const int* __restrict__ ei, const int* __restrict__ tids,
    const float* __restrict__ Wf, const float* __restrict__ bf_,
    float* __restrict__ out, int Etr, int E) {
    const int lane = threadIdx.x & 63;
    const int wv   = threadIdx.x >> 6;
    float wfr[8][N_CLS];
    #pragma unroll
    for (int r = 0; r < 8; ++r)
        #pragma unroll
        for (int c = 0; c < N_CLS; ++c)
            wfr[r][c] = Wf[(lane * 8 + r) * N_CLS + c];
    float bfr[N_CLS];
    #pragma unroll
    for (int c = 0; c < N_CLS; ++c) bfr[c] = bf_[c];

    const int wid  = blockIdx.x * 4 + wv;
    const int step = gridDim.x * 4;
    for (int t = wid; t < Etr; t += step) {
        const int eid = tids[t];
        const size_t a = (size_t)ei[eid] * H_DIM + lane * 8;
        const size_t b = (size_t)ei[E + eid] * H_DIM + lane * 8;
        const ushort8 ah = *(const ushort8*)(hh + a);
        const ushort8 al = *(const ushort8*)(hl + a);
        const ushort8 bh = *(const ushort8*)(hh + b);
        const ushort8 bl = *(const ushort8*)(hl + b);
        float acc[N_CLS] = {0.f, 0.f, 0.f, 0.f, 0.f, 0.f, 0.f};
        #pragma unroll
        for (int r = 0; r < 8; ++r) {
            const float va = bf2f(ah[r]) + bf2f(al[r]);
            const float vb = bf2f(bh[r]) + bf2f(bl[r]);
            const float e = va * vb;
            #pragma unroll
            for (int c = 0; c < N_CLS; ++c) acc[c] = fmaf(e, wfr[r][c], acc[c]);
        }
        #pragma unroll
        for (int o = 32; o; o >>= 1)
            #pragma unroll
            for (int c = 0; c < N_CLS; ++c) acc[c] += __shfl_xor(acc[c], o, 64);
        if (lane == 0) {
            #pragma unroll
            for (int c = 0; c < N_CLS; ++c) out[(size_t)t * N_CLS + c] = acc[c] + bfr[c];
        }
    }
}

// ---------------- launch ----------------

extern "C" void kernel_launch(void* const* d_in, const int* in_sizes, int n_in,
                              void* d_out, int out_size, void* d_ws, size_t ws_size,
                              hipStream_t stream) {
    const float* x    = (const float*)d_in[0];
    const int*   ei   = (const int*)d_in[1];
    const int*   tids = (const int*)d_in[2];
    const float* eps1 = (const float*)d_in[3];
    const float* W1a  = (const float*)d_in[4];
    const float* b1a  = (const float*)d_in[5];
    const float* W1b  = (const float*)d_in[6];
    const float* b1b  = (const float*)d_in[7];
    const float* g1p  = (const float*)d_in[8];
    const float* be1  = (const float*)d_in[9];
    const float* rm1  = (const float*)d_in[10];
    const float* rv1  = (const float*)d_in[11];
    const float* eps2 = (const float*)d_in[12];
    const float* W2a  = (const float*)d_in[13];
    const float* b2a  = (const float*)d_in[14];
    const float* g2p  = (const float*)d_in[15];
    const float* be2  = (const float*)d_in[16];
    const float* rm2  = (const float*)d_in[17];
    const float* rv2  = (const float*)d_in[18];
    const float* Wl   = (const float*)d_in[19];
    const float* bl   = (const float*)d_in[20];
    const float* Wf   = (const float*)d_in[21];
    const float* bf   = (const float*)d_in[22];
    float* out = (float*)d_out;

    const int E   = in_sizes[1] / 2;
    const int Etr = in_sizes[2];

    char* ws = (char*)d_ws;
    size_t off = 0;
    auto alloc = [&](size_t bytes) -> char* {
        char* p = ws + off;
        off += (bytes + 255) & ~(size_t)255;
        return p;
    };
    int*    counts  = (int*)alloc((size_t)N_NODES * 4);
    int*    offsets = (int*)alloc((size_t)(N_NODES + 1) * 4);
    int*    cursor  = (int*)alloc((size_t)N_NODES * 4);
    int*    csr_src = (int*)alloc((size_t)E * 4);
    ushort* h0h = (ushort*)alloc((size_t)M_PAD * F_IN * 2);
    ushort* h0l = (ushort*)alloc((size_t)M_PAD * F_IN * 2);
    ushort* Ahh = (ushort*)alloc((size_t)M_PAD * H_DIM * 2);  // pair A
    ushort* Ahl = (ushort*)alloc((size_t)M_PAD * H_DIM * 2);
    ushort* Bhh = (ushort*)alloc((size_t)M_PAD * H_DIM * 2);  // pair B
    ushort* Bhl = (ushort*)alloc((size_t)M_PAD * H_DIM * 2);
    ushort* wt1a_h = (ushort*)alloc((size_t)H_DIM * F_IN * 2);
    ushort* wt1a_l = (ushort*)alloc((size_t)H_DIM * F_IN * 2);
    ushort* wt1b_h = (ushort*)alloc((size_t)H_DIM * H_DIM * 2);
    ushort* wt1b_l = (ushort*)alloc((size_t)H_DIM * H_DIM * 2);
    ushort* wt2a_h = (ushort*)alloc((size_t)H_DIM * H_DIM * 2);
    ushort* wt2a_l = (ushort*)alloc((size_t)H_DIM * H_DIM * 2);
    ushort* wtl_h  = (ushort*)alloc((size_t)H_DIM * H_DIM * 2);
    ushort* wtl_l  = (ushort*)alloc((size_t)H_DIM * H_DIM * 2);
    (void)ws_size; (void)n_in; (void)out_size;

    // CSR by dst
    k_zero_i32<<<(N_NODES + 255) / 256, 256, 0, stream>>>(counts, N_NODES);
    k_hist<<<(E + 255) / 256, 256, 0, stream>>>(ei, counts, E);
    k_scan<<<1, 1024, 0, stream>>>(counts, offsets, cursor, N_NODES, E);
    k_scatter<<<(E + 255) / 256, 256, 0, stream>>>(ei, cursor, csr_src, E);

    // weight hi/lo transposed splits
    k_wsplit<<<(H_DIM * F_IN + 255) / 256, 256, 0, stream>>>(W1a, wt1a_h, wt1a_l, F_IN, H_DIM);
    k_wsplit<<<(H_DIM * H_DIM + 255) / 256, 256, 0, stream>>>(W1b, wt1b_h, wt1b_l, H_DIM, H_DIM);
    k_wsplit<<<(H_DIM * H_DIM + 255) / 256, 256, 0, stream>>>(W2a, wt2a_h, wt2a_l, H_DIM, H_DIM);
    k_wsplit<<<(H_DIM * H_DIM + 255) / 256, 256, 0, stream>>>(Wl,  wtl_h,  wtl_l,  H_DIM, H_DIM);

    // h0 = (1+eps1)*x + agg(x)  -> pair (wave per node, 4 nodes/block)
    k_agg_f32<<<(N_NODES + 3) / 4, 256, 0, stream>>>(x, csr_src, offsets, eps1, h0h, h0l);

    dim3 gdim(M_PAD / 64, H_DIM / 128);   // 158 x 4 = 632 blocks
    // h1 = relu(h0 @ W1a + b1a)            -> pair A
    k_gemm_mfma<0><<<gdim, 256, 0, stream>>>(h0h, h0l, wt1a_h, wt1a_l, b1a,
                                             nullptr, nullptr, nullptr, nullptr,
                                             Ahh, Ahl, F_IN, H_DIM);
    // h2 = bn1(relu(h1 @ W1b + b1b))       -> pair B
    k_gemm_mfma<1><<<gdim, 256, 0, stream>>>(Ahh, Ahl, wt1b_h, wt1b_l, b1b,
                                             g1p, be1, rm1, rv1,
                                             Bhh, Bhl, H_DIM, H_DIM);
    // h3 = (1+eps2)*h2 + agg(h2)           -> pair A (wave per node)
    k_agg_pair<<<(N_NODES + 3) / 4, 256, 0, stream>>>(Bhh, Bhl, csr_src, offsets, eps2, Ahh, Ahl);
    // h4 = bn2(relu(h3 @ W2a + b2a))       -> pair B
    k_gemm_mfma<1><<<gdim, 256, 0, stream>>>(Ahh, Ahl, wt2a_h, wt2a_l, b2a,
                                             g2p, be2, rm2, rv2,
                                             Bhh, Bhl, H_DIM, H_DIM);
    // h5 = relu(h4 @ Wl + bl)              -> pair A
    k_gemm_mfma<0><<<gdim, 256, 0, stream>>>(Bhh, Bhl, wtl_h, wtl_l, bl,
                                             nullptr, nullptr, nullptr, nullptr,
                                             Ahh, Ahl, H_DIM, H_DIM);
    // edge head (grid-stride, wf-in-registers)
    k_edge<<<2048, 256, 0, stream>>>(Ahh, Ahl, ei, tids, Wf, bf, out, Etr, E);
}

// Round 10
// 326.320 us; speedup vs baseline: 1.8012x; 1.0342x over previous
//
#include <hip/hip_runtime.h>
#include <hip/hip_bf16.h>

#define N_NODES 10000
#define M_PAD   10112   // 158*64
#define F_IN    128
#define H_DIM   512
#define N_CLS   7
#define NCHUNK  8
#define CCOLS   (H_DIM / NCHUNK)   // 64

typedef __bf16  bf16x8  __attribute__((ext_vector_type(8)));
typedef float   f32x4   __attribute__((ext_vector_type(4)));
typedef ushort  ushort8 __attribute__((ext_vector_type(8)));

__device__ __forceinline__ ushort f2bf(float f) {
    union { float f; unsigned u; } x; x.f = f;
    unsigned r = x.u + 0x7fffu + ((x.u >> 16) & 1u);
    return (ushort)(r >> 16);
}
__device__ __forceinline__ float bf2f(ushort h) {
    union { unsigned u; float f; } x; x.u = ((unsigned)h) << 16;
    return x.f;
}

__device__ __forceinline__ void gload16(const void* g, void* l) {
    __builtin_amdgcn_global_load_lds(
        (const __attribute__((address_space(1))) void*)g,
        (__attribute__((address_space(3))) void*)l, 16, 0, 0);
}

// ---------------- CSR build ----------------

__global__ void k_zero_i32(int* __restrict__ p, int n) {
    int i = blockIdx.x * blockDim.x + threadIdx.x;
    if (i < n) p[i] = 0;
}

__global__ void k_hist(const int* __restrict__ ei, int* __restrict__ counts, int E) {
    int e = blockIdx.x * blockDim.x + threadIdx.x;
    if (e < E) atomicAdd(&counts[ei[E + e]], 1);  // dst
}

__global__ __launch_bounds__(1024) void k_scan(const int* __restrict__ counts,
                                               int* __restrict__ offsets,
                                               int* __restrict__ cursor,
                                               int N, int E) {
    __shared__ int sm[1024];
    int t = threadIdx.x;
    int base = t * 10;
    int loc[10];
    int s = 0;
    #pragma unroll
    for (int i = 0; i < 10; ++i) {
        int idx = base + i;
        int c = (idx < N) ? counts[idx] : 0;
        loc[i] = s;
        s += c;
    }
    sm[t] = s;
    __syncthreads();
    for (int off = 1; off < 1024; off <<= 1) {
        int v = (t >= off) ? sm[t - off] : 0;
        __syncthreads();
        sm[t] += v;
        __syncthreads();
    }
    int excl = sm[t] - s;
    #pragma unroll
    for (int i = 0; i < 10; ++i) {
        int idx = base + i;
        if (idx < N) {
            int o = excl + loc[i];
            offsets[idx] = o;
            cursor[idx] = o;
        }
    }
    if (t == 0) offsets[N] = E;
}

__global__ void k_scatter(const int* __restrict__ ei, int* __restrict__ cursor,
                          int* __restrict__ csr_src, int E) {
    int e = blockIdx.x * blockDim.x + threadIdx.x;
    if (e < E) {
        int d = ei[E + e];
        int pos = atomicAdd(&cursor[d], 1);
        csr_src[pos] = ei[e];
    }
}

// ---------------- weight split: W (K x N fp32) -> Wt_hi/Wt_lo (N x K bf16) ----------------

__global__ void k_wsplit(const float* __restrict__ W, ushort* __restrict__ Th,
                         ushort* __restrict__ Tl, int K, int N) {
    int idx = blockIdx.x * blockDim.x + threadIdx.x;
    if (idx >= K * N) return;
    int n = idx / K, k = idx % K;
    float w = W[(size_t)k * N + n];
    ushort hb = f2bf(w);
    Th[idx] = hb;
    Tl[idx] = f2bf(w - bf2f(hb));
}

// ---------------- GIN agg, fp32 input (F=128): wave per node, float2/lane ----------------

__global__ __launch_bounds__(256) void k_agg_f32(
    const float* __restrict__ X, const int* __restrict__ csr,
    const int* __restrict__ offs, const float* __restrict__ eps,
    ushort* __restrict__ Oh, ushort* __restrict__ Ol) {
    const int wv = threadIdx.x >> 6, lane = threadIdx.x & 63;
    const int n = blockIdx.x * 4 + wv;
    if (n >= N_NODES) return;
    const int c0 = lane * 2;
    const int s0 = offs[n], s1 = offs[n + 1];
    float a0 = 0.f, a1 = 0.f;
    int i = s0;
    for (; i + 1 < s1; i += 2) {
        const float2 v0 = *(const float2*)(X + (size_t)csr[i] * F_IN + c0);
        const float2 v1 = *(const float2*)(X + (size_t)csr[i + 1] * F_IN + c0);
        a0 += v0.x + v1.x;
        a1 += v0.y + v1.y;
    }
    if (i < s1) {
        const float2 v = *(const float2*)(X + (size_t)csr[i] * F_IN + c0);
        a0 += v.x; a1 += v.y;
    }
    const float2 sv = *(const float2*)(X + (size_t)n * F_IN + c0);
    const float e = 1.f + eps[0];
    const float v0 = e * sv.x + a0;
    const float v1 = e * sv.y + a1;
    ushort2 oh, ol;
    oh.x = f2bf(v0); ol.x = f2bf(v0 - bf2f(oh.x));
    oh.y = f2bf(v1); ol.y = f2bf(v1 - bf2f(oh.y));
    const size_t o = (size_t)n * F_IN + c0;
    *(ushort2*)(Oh + o) = oh;
    *(ushort2*)(Ol + o) = ol;
}

// ---------------- GIN agg, pair input (F=512): XCD column-chunked ----------------
// Chunk = blockIdx&7 -> 64 cols (2.56 MB hi+lo) which the round-robin
// workgroup->XCD dispatch pins to one XCD's L2 -> gathers become L2-hits
// instead of 8x-replicated HBM streams (round-9 floor: FETCH=141MB ~= 8 XCD
// x 20.5MB working set). 16 thr/node: 8 col-subgroups x {hi,lo} plane;
// hi/lo partials combined via shfl_xor(8).

__global__ __launch_bounds__(256) void k_agg_pair(
    const ushort* __restrict__ Xh, const ushort* __restrict__ Xl,
    const int* __restrict__ csr, const int* __restrict__ offs,
    const float* __restrict__ eps,
    ushort* __restrict__ Oh, ushort* __restrict__ Ol) {
    const int chunk = blockIdx.x & (NCHUNK - 1);
    const int grp   = blockIdx.x >> 3;          // 0..624
    const int tid   = threadIdx.x;
    const int n     = grp * 16 + (tid >> 4);    // 16 nodes/block
    const int sub   = tid & 15;
    const int plane = sub >> 3;                 // 0 = hi, 1 = lo
    const int col   = chunk * CCOLS + (sub & 7) * 8;
    const ushort* __restrict__ X = plane ? Xl : Xh;

    const int s0 = offs[n], s1 = offs[n + 1];
    float acc[8] = {0.f, 0.f, 0.f, 0.f, 0.f, 0.f, 0.f, 0.f};
    for (int i = s0; i < s1; ++i) {
        const ushort8 v = *(const ushort8*)(X + (size_t)csr[i] * H_DIM + col);
        #pragma unroll
        for (int r = 0; r < 8; ++r) acc[r] += bf2f(v[r]);
    }
    // self term with (1+eps), per plane
    {
        const ushort8 sv = *(const ushort8*)(X + (size_t)n * H_DIM + col);
        const float e = 1.f + eps[0];
        #pragma unroll
        for (int r = 0; r < 8; ++r) acc[r] += e * bf2f(sv[r]);
    }
    // combine hi+lo partials (partner lane = tid^8, same node, same cols)
    float tot[8];
    #pragma unroll
    for (int r = 0; r < 8; ++r) tot[r] = acc[r] + __shfl_xor(acc[r], 8, 64);
    if (plane == 0) {
        ushort8 oh, ol;
        #pragma unroll
        for (int r = 0; r < 8; ++r) {
            oh[r] = f2bf(tot[r]);
            ol[r] = f2bf(tot[r] - bf2f(oh[r]));
        }
        const size_t o = (size_t)n * H_DIM + col;
        *(ushort8*)(Oh + o) = oh;
        *(ushort8*)(Ol + o) = ol;
    }
}

// ---------------- split-bf16 MFMA GEMM ----------------
// C = ep(A @ W + bias); A as hi/lo pair (M x K), W as hi/lo pair transposed [N][K].
// 64x128 tile (grid 158x4 = 632 blocks), BK=32, 4 waves 2x2 (32x64 each),
// mfma_f32_16x16x32_bf16; 3 MFMA terms: hi*hi + hi*lo + lo*hi.
// ep: relu, then optional BN. Output written as hi/lo bf16 pair.

template <int DO_BN>
__global__ __launch_bounds__(256) void k_gemm_mfma(
    const ushort* __restrict__ Ah, const ushort* __restrict__ Al,
    const ushort* __restrict__ Wh, const ushort* __restrict__ Wlo,
    const float* __restrict__ bias,
    const float* __restrict__ g, const float* __restrict__ be,
    const float* __restrict__ rm, const float* __restrict__ rv,
    ushort* __restrict__ Oh, ushort* __restrict__ Ol,
    int K, int Nout) {
    __shared__ __align__(16) ushort As_h[64][32];
    __shared__ __align__(16) ushort As_l[64][32];
    __shared__ __align__(16) ushort Bs_h[128][32];
    __shared__ __align__(16) ushort Bs_l[128][32];

    const int tid  = threadIdx.x;
    const int lane = tid & 63;
    const int wid  = tid >> 6;
    const int wm   = wid >> 1, wn = wid & 1;   // 2x2 waves, wave tile 32x64
    const int bm = blockIdx.x * 64, bn = blockIdx.y * 128;
    const int rsel = lane & 15;
    const int kh   = (lane >> 4) * 8;

    f32x4 acc[2][4];
    #pragma unroll
    for (int m = 0; m < 2; ++m)
        #pragma unroll
        for (int n = 0; n < 4; ++n) {
            acc[m][n][0] = 0.f; acc[m][n][1] = 0.f;
            acc[m][n][2] = 0.f; acc[m][n][3] = 0.f;
        }

    for (int k0 = 0; k0 < K; k0 += 32) {
        {
            const int off = tid * 16;          // A: 64x32 = 4KB/plane
            const int row = off >> 6;
            const int ke  = (off & 63) >> 1;
            const size_t ga = (size_t)(bm + row) * K + (k0 + ke);
            gload16(Ah + ga, (char*)As_h + off);
            gload16(Al + ga, (char*)As_l + off);
        }
        #pragma unroll
        for (int c = 0; c < 2; ++c) {
            const int off = tid * 16 + c * 4096;  // B: 128x32 = 8KB/plane
            const int row = off >> 6;
            const int ke  = (off & 63) >> 1;
            const size_t gb = (size_t)(bn + row) * K + (k0 + ke);
            gload16(Wh + gb,  (char*)Bs_h + off);
            gload16(Wlo + gb, (char*)Bs_l + off);
        }
        __syncthreads();
        bf16x8 a_h[2], a_l[2], b_h[4], b_l[4];
        #pragma unroll
        for (int m = 0; m < 2; ++m) {
            const int r = wm * 32 + m * 16 + rsel;
            a_h[m] = *(const bf16x8*)&As_h[r][kh];
            a_l[m] = *(const bf16x8*)&As_l[r][kh];
        }
        #pragma unroll
        for (int n = 0; n < 4; ++n) {
            const int r = wn * 64 + n * 16 + rsel;
            b_h[n] = *(const bf16x8*)&Bs_h[r][kh];
            b_l[n] = *(const bf16x8*)&Bs_l[r][kh];
        }
        #pragma unroll
        for (int m = 0; m < 2; ++m)
            #pragma unroll
            for (int n = 0; n < 4; ++n) {
                acc[m][n] = __builtin_amdgcn_mfma_f32_16x16x32_bf16(a_h[m], b_h[n], acc[m][n], 0, 0, 0);
                acc[m][n] = __builtin_amdgcn_mfma_f32_16x16x32_bf16(a_h[m], b_l[n], acc[m][n], 0, 0, 0);
                acc[m][n] = __builtin_amdgcn_mfma_f32_16x16x32_bf16(a_l[m], b_h[n], acc[m][n], 0, 0, 0);
            }
        __syncthreads();
    }

    float bs[4], sc[4], sh[4];
    int cols[4];
    #pragma unroll
    for (int n = 0; n < 4; ++n) {
        const int col = bn + wn * 64 + n * 16 + rsel;
        cols[n] = col;
        bs[n] = bias[col];
        if (DO_BN) {
            const float s = g[col] * rsqrtf(rv[col] + 1e-5f);
            sc[n] = s;
            sh[n] = be[col] - rm[col] * s;
        } else {
            sc[n] = 0.f; sh[n] = 0.f;
        }
    }
    #pragma unroll
    for (int m = 0; m < 2; ++m) {
        #pragma unroll
        for (int r = 0; r < 4; ++r) {
            const int row = bm + wm * 32 + m * 16 + (lane >> 4) * 4 + r;
            #pragma unroll
            for (int n = 0; n < 4; ++n) {
                float v = acc[m][n][r] + bs[n];
                v = fmaxf(v, 0.f);
                if (DO_BN) v = v * sc[n] + sh[n];
                const ushort hb = f2bf(v);
                const ushort lb = f2bf(v - bf2f(hb));
                const size_t o = (size_t)row * Nout + cols[n];
                Oh[o] = hb;
                Ol[o] = lb;
            }
        }
    }
}

// ---------------- edge head: out[t] = (h[a]*h[b]) @ Wf + bf ----------------
// Wf in registers (lane owns k-rows lane*8..lane*8+7); grid-stride waves.

__global__ __launch_bounds__(256) void k_edge(
    const ushort* __restrict__ hh, const ushort* __restrict__ hl,
    const int* __restrict__ ei, const int* __restrict__ tids,
    const float* __restrict__ Wf, const float* __restrict__ bf_,
    float* __restrict__ out, int Etr, int E) {
    const int lane = threadIdx.x & 63;
    const int wv   = threadIdx.x >> 6;
    float wfr[8][N_CLS];
    #pragma unroll
    for (int r = 0; r < 8; ++r)
        #pragma unroll
        for (int c = 0; c < N_CLS; ++c)
            wfr[r][c] = Wf[(lane * 8 + r) * N_CLS + c];
    float bfr[N_CLS];
    #pragma unroll
    for (int c = 0; c < N_CLS; ++c) bfr[c] = bf_[c];

    const int wid  = blockIdx.x * 4 + wv;
    const int step = gridDim.x * 4;
    for (int t = wid; t < Etr; t += step) {
        const int eid = tids[t];
        const size_t a = (size_t)ei[eid] * H_DIM + lane * 8;
        const size_t b = (size_t)ei[E + eid] * H_DIM + lane * 8;
        const ushort8 ah = *(const ushort8*)(hh + a);
        const ushort8 al = *(const ushort8*)(hl + a);
        const ushort8 bh = *(const ushort8*)(hh + b);
        const ushort8 bl = *(const ushort8*)(hl + b);
        float acc[N_CLS] = {0.f, 0.f, 0.f, 0.f, 0.f, 0.f, 0.f};
        #pragma unroll
        for (int r = 0; r < 8; ++r) {
            const float va = bf2f(ah[r]) + bf2f(al[r]);
            const float vb = bf2f(bh[r]) + bf2f(bl[r]);
            const float e = va * vb;
            #pragma unroll
            for (int c = 0; c < N_CLS; ++c) acc[c] = fmaf(e, wfr[r][c], acc[c]);
        }
        #pragma unroll
        for (int o = 32; o; o >>= 1)
            #pragma unroll
            for (int c = 0; c < N_CLS; ++c) acc[c] += __shfl_xor(acc[c], o, 64);
        if (lane == 0) {
            #pragma unroll
            for (int c = 0; c < N_CLS; ++c) out[(size_t)t * N_CLS + c] = acc[c] + bfr[c];
        }
    }
}

// ---------------- launch ----------------

extern "C" void kernel_launch(void* const* d_in, const int* in_sizes, int n_in,
                              void* d_out, int out_size, void* d_ws, size_t ws_size,
                              hipStream_t stream) {
    const float* x    = (const float*)d_in[0];
    const int*   ei   = (const int*)d_in[1];
    const int*   tids = (const int*)d_in[2];
    const float* eps1 = (const float*)d_in[3];
    const float* W1a  = (const float*)d_in[4];
    const float* b1a  = (const float*)d_in[5];
    const float* W1b  = (const float*)d_in[6];
    const float* b1b  = (const float*)d_in[7];
    const float* g1p  = (const float*)d_in[8];
    const float* be1  = (const float*)d_in[9];
    const float* rm1  = (const float*)d_in[10];
    const float* rv1  = (const float*)d_in[11];
    const float* eps2 = (const float*)d_in[12];
    const float* W2a  = (const float*)d_in[13];
    const float* b2a  = (const float*)d_in[14];
    const float* g2p  = (const float*)d_in[15];
    const float* be2  = (const float*)d_in[16];
    const float* rm2  = (const float*)d_in[17];
    const float* rv2  = (const float*)d_in[18];
    const float* Wl   = (const float*)d_in[19];
    const float* bl   = (const float*)d_in[20];
    const float* Wf   = (const float*)d_in[21];
    const float* bf   = (const float*)d_in[22];
    float* out = (float*)d_out;

    const int E   = in_sizes[1] / 2;
    const int Etr = in_sizes[2];

    char* ws = (char*)d_ws;
    size_t off = 0;
    auto alloc = [&](size_t bytes) -> char* {
        char* p = ws + off;
        off += (bytes + 255) & ~(size_t)255;
        return p;
    };
    int*    counts  = (int*)alloc((size_t)N_NODES * 4);
    int*    offsets = (int*)alloc((size_t)(N_NODES + 1) * 4);
    int*    cursor  = (int*)alloc((size_t)N_NODES * 4);
    int*    csr_src = (int*)alloc((size_t)E * 4);
    ushort* h0h = (ushort*)alloc((size_t)M_PAD * F_IN * 2);
    ushort* h0l = (ushort*)alloc((size_t)M_PAD * F_IN * 2);
    ushort* Ahh = (ushort*)alloc((size_t)M_PAD * H_DIM * 2);  // pair A
    ushort* Ahl = (ushort*)alloc((size_t)M_PAD * H_DIM * 2);
    ushort* Bhh = (ushort*)alloc((size_t)M_PAD * H_DIM * 2);  // pair B
    ushort* Bhl = (ushort*)alloc((size_t)M_PAD * H_DIM * 2);
    ushort* wt1a_h = (ushort*)alloc((size_t)H_DIM * F_IN * 2);
    ushort* wt1a_l = (ushort*)alloc((size_t)H_DIM * F_IN * 2);
    ushort* wt1b_h = (ushort*)alloc((size_t)H_DIM * H_DIM * 2);
    ushort* wt1b_l = (ushort*)alloc((size_t)H_DIM * H_DIM * 2);
    ushort* wt2a_h = (ushort*)alloc((size_t)H_DIM * H_DIM * 2);
    ushort* wt2a_l = (ushort*)alloc((size_t)H_DIM * H_DIM * 2);
    ushort* wtl_h  = (ushort*)alloc((size_t)H_DIM * H_DIM * 2);
    ushort* wtl_l  = (ushort*)alloc((size_t)H_DIM * H_DIM * 2);
    (void)ws_size; (void)n_in; (void)out_size;

    // CSR by dst
    k_zero_i32<<<(N_NODES + 255) / 256, 256, 0, stream>>>(counts, N_NODES);
    k_hist<<<(E + 255) / 256, 256, 0, stream>>>(ei, counts, E);
    k_scan<<<1, 1024, 0, stream>>>(counts, offsets, cursor, N_NODES, E);
    k_scatter<<<(E + 255) / 256, 256, 0, stream>>>(ei, cursor, csr_src, E);

    // weight hi/lo transposed splits
    k_wsplit<<<(H_DIM * F_IN + 255) / 256, 256, 0, stream>>>(W1a, wt1a_h, wt1a_l, F_IN, H_DIM);
    k_wsplit<<<(H_DIM * H_DIM + 255) / 256, 256, 0, stream>>>(W1b, wt1b_h, wt1b_l, H_DIM, H_DIM);
    k_wsplit<<<(H_DIM * H_DIM + 255) / 256, 256, 0, stream>>>(W2a, wt2a_h, wt2a_l, H_DIM, H_DIM);
    k_wsplit<<<(H_DIM * H_DIM + 255) / 256, 256, 0, stream>>>(Wl,  wtl_h,  wtl_l,  H_DIM, H_DIM);

    // h0 = (1+eps1)*x + agg(x)  -> pair (wave per node, 4 nodes/block)
    k_agg_f32<<<(N_NODES + 3) / 4, 256, 0, stream>>>(x, csr_src, offsets, eps1, h0h, h0l);

    dim3 gdim(M_PAD / 64, H_DIM / 128);   // 158 x 4 = 632 blocks
    // h1 = relu(h0 @ W1a + b1a)            -> pair A
    k_gemm_mfma<0><<<gdim, 256, 0, stream>>>(h0h, h0l, wt1a_h, wt1a_l, b1a,
                                             nullptr, nullptr, nullptr, nullptr,
                                             Ahh, Ahl, F_IN, H_DIM);
    // h2 = bn1(relu(h1 @ W1b + b1b))       -> pair B
    k_gemm_mfma<1><<<gdim, 256, 0, stream>>>(Ahh, Ahl, wt1b_h, wt1b_l, b1b,
                                             g1p, be1, rm1, rv1,
                                             Bhh, Bhl, H_DIM, H_DIM);
    // h3 = (1+eps2)*h2 + agg(h2)           -> pair A (XCD column-chunked)
    k_agg_pair<<<(N_NODES / 16) * NCHUNK, 256, 0, stream>>>(Bhh, Bhl, csr_src, offsets, eps2, Ahh, Ahl);
    // h4 = bn2(relu(h3 @ W2a + b2a))       -> pair B
    k_gemm_mfma<1><<<gdim, 256, 0, stream>>>(Ahh, Ahl, wt2a_h, wt2a_l, b2a,
                                             g2p, be2, rm2, rv2,
                                             Bhh, Bhl, H_DIM, H_DIM);
    // h5 = relu(h4 @ Wl + bl)              -> pair A
    k_gemm_mfma<0><<<gdim, 256, 0, stream>>>(Bhh, Bhl, wtl_h, wtl_l, bl,
                                             nullptr, nullptr, nullptr, nullptr,
                                             Ahh, Ahl, H_DIM, H_DIM);
    // edge head (grid-stride, wf-in-registers)
    k_edge<<<2048, 256, 0, stream>>>(Ahh, Ahl, ei, tids, Wf, bf, out, Etr, E);
}

// Round 12
// 317.303 us; speedup vs baseline: 1.8524x; 1.0284x over previous
//
#include <hip/hip_runtime.h>
#include <hip/hip_bf16.h>

#define N_NODES 10000
#define M_PAD   10112   // 158*64
#define F_IN    128
#define H_DIM   512
#define N_CLS   7
#define NCHUNK  8
#define CCOLS   (H_DIM / NCHUNK)   // 64

typedef __bf16  bf16x8  __attribute__((ext_vector_type(8)));
typedef float   f32x4   __attribute__((ext_vector_type(4)));
typedef ushort  ushort8 __attribute__((ext_vector_type(8)));

__device__ __forceinline__ ushort f2bf(float f) {
    union { float f; unsigned u; } x; x.f = f;
    unsigned r = x.u + 0x7fffu + ((x.u >> 16) & 1u);
    return (ushort)(r >> 16);
}
__device__ __forceinline__ float bf2f(ushort h) {
    union { unsigned u; float f; } x; x.u = ((unsigned)h) << 16;
    return x.f;
}

__device__ __forceinline__ void gload16(const void* g, void* l) {
    __builtin_amdgcn_global_load_lds(
        (const __attribute__((address_space(1))) void*)g,
        (__attribute__((address_space(3))) void*)l, 16, 0, 0);
}

// ---------------- CSR build ----------------

__global__ void k_zero_i32(int* __restrict__ p, int n) {
    int i = blockIdx.x * blockDim.x + threadIdx.x;
    if (i < n) p[i] = 0;
}

__global__ void k_hist(const int* __restrict__ ei, int* __restrict__ counts, int E) {
    int e = blockIdx.x * blockDim.x + threadIdx.x;
    if (e < E) atomicAdd(&counts[ei[E + e]], 1);  // dst
}

__global__ __launch_bounds__(1024) void k_scan(const int* __restrict__ counts,
                                               int* __restrict__ offsets,
                                               int* __restrict__ cursor,
                                               int N, int E) {
    __shared__ int sm[1024];
    int t = threadIdx.x;
    int base = t * 10;
    int loc[10];
    int s = 0;
    #pragma unroll
    for (int i = 0; i < 10; ++i) {
        int idx = base + i;
        int c = (idx < N) ? counts[idx] : 0;
        loc[i] = s;
        s += c;
    }
    sm[t] = s;
    __syncthreads();
    for (int off = 1; off < 1024; off <<= 1) {
        int v = (t >= off) ? sm[t - off] : 0;
        __syncthreads();
        sm[t] += v;
        __syncthreads();
    }
    int excl = sm[t] - s;
    #pragma unroll
    for (int i = 0; i < 10; ++i) {
        int idx = base + i;
        if (idx < N) {
            int o = excl + loc[i];
            offsets[idx] = o;
            cursor[idx] = o;
        }
    }
    if (t == 0) offsets[N] = E;
}

__global__ void k_scatter(const int* __restrict__ ei, int* __restrict__ cursor,
                          int* __restrict__ csr_src, int E) {
    int e = blockIdx.x * blockDim.x + threadIdx.x;
    if (e < E) {
        int d = ei[E + e];
        int pos = atomicAdd(&cursor[d], 1);
        csr_src[pos] = ei[e];
    }
}

// ---------------- weight split: W (K x N fp32) -> Wt_hi/Wt_lo (N x K bf16) ----------------
// LDS 32x33 tile transpose: coalesced read AND coalesced write (old version's
// stride-N reads over-fetched 16x: 64B line per 4B used).

__global__ __launch_bounds__(256) void k_wsplit(const float* __restrict__ W,
                                                ushort* __restrict__ Th,
                                                ushort* __restrict__ Tl,
                                                int K, int N) {
    __shared__ float tile[32][33];
    const int bk = blockIdx.x * 32;
    const int bn = blockIdx.y * 32;
    const int c  = threadIdx.x & 31;
    const int r0 = threadIdx.x >> 5;   // 0..7
    #pragma unroll
    for (int i = 0; i < 4; ++i) {
        const int r = r0 + i * 8;
        tile[r][c] = W[(size_t)(bk + r) * N + bn + c];
    }
    __syncthreads();
    #pragma unroll
    for (int i = 0; i < 4; ++i) {
        const int r = r0 + i * 8;          // n-offset
        const float w = tile[c][r];        // = W[bk+c][bn+r]
        const ushort hb = f2bf(w);
        const size_t o = (size_t)(bn + r) * K + bk + c;   // consecutive c -> coalesced
        Th[o] = hb;
        Tl[o] = f2bf(w - bf2f(hb));
    }
}

// ---------------- GIN agg, fp32 input (F=128): wave per node, float2/lane ----------------

__global__ __launch_bounds__(256) void k_agg_f32(
    const float* __restrict__ X, const int* __restrict__ csr,
    const int* __restrict__ offs, const float* __restrict__ eps,
    ushort* __restrict__ Oh, ushort* __restrict__ Ol) {
    const int wv = threadIdx.x >> 6, lane = threadIdx.x & 63;
    const int n = blockIdx.x * 4 + wv;
    if (n >= N_NODES) return;
    const int c0 = lane * 2;
    const int s0 = offs[n], s1 = offs[n + 1];
    float a0 = 0.f, a1 = 0.f;
    int i = s0;
    for (; i + 1 < s1; i += 2) {
        const float2 v0 = *(const float2*)(X + (size_t)csr[i] * F_IN + c0);
        const float2 v1 = *(const float2*)(X + (size_t)csr[i + 1] * F_IN + c0);
        a0 += v0.x + v1.x;
        a1 += v0.y + v1.y;
    }
    if (i < s1) {
        const float2 v = *(const float2*)(X + (size_t)csr[i] * F_IN + c0);
        a0 += v.x; a1 += v.y;
    }
    const float2 sv = *(const float2*)(X + (size_t)n * F_IN + c0);
    const float e = 1.f + eps[0];
    const float v0 = e * sv.x + a0;
    const float v1 = e * sv.y + a1;
    ushort2 oh, ol;
    oh.x = f2bf(v0); ol.x = f2bf(v0 - bf2f(oh.x));
    oh.y = f2bf(v1); ol.y = f2bf(v1 - bf2f(oh.y));
    const size_t o = (size_t)n * F_IN + c0;
    *(ushort2*)(Oh + o) = oh;
    *(ushort2*)(Ol + o) = ol;
}

// ---------------- GIN agg, pair input (F=512): XCD column-chunked ----------------

__global__ __launch_bounds__(256) void k_agg_pair(
    const ushort* __restrict__ Xh, const ushort* __restrict__ Xl,
    const int* __restrict__ csr, const int* __restrict__ offs,
    const float* __restrict__ eps,
    ushort* __restrict__ Oh, ushort* __restrict__ Ol) {
    const int chunk = blockIdx.x & (NCHUNK - 1);
    const int grp   = blockIdx.x >> 3;
    const int tid   = threadIdx.x;
    const int n     = grp * 16 + (tid >> 4);
    const int sub   = tid & 15;
    const int plane = sub >> 3;
    const int col   = chunk * CCOLS + (sub & 7) * 8;
    const ushort* __restrict__ X = plane ? Xl : Xh;

    const int s0 = offs[n], s1 = offs[n + 1];
    float acc[8] = {0.f, 0.f, 0.f, 0.f, 0.f, 0.f, 0.f, 0.f};
    for (int i = s0; i < s1; ++i) {
        const ushort8 v = *(const ushort8*)(X + (size_t)csr[i] * H_DIM + col);
        #pragma unroll
        for (int r = 0; r < 8; ++r) acc[r] += bf2f(v[r]);
    }
    {
        const ushort8 sv = *(const ushort8*)(X + (size_t)n * H_DIM + col);
        const float e = 1.f + eps[0];
        #pragma unroll
        for (int r = 0; r < 8; ++r) acc[r] += e * bf2f(sv[r]);
    }
    float tot[8];
    #pragma unroll
    for (int r = 0; r < 8; ++r) tot[r] = acc[r] + __shfl_xor(acc[r], 8, 64);
    if (plane == 0) {
        ushort8 oh, ol;
        #pragma unroll
        for (int r = 0; r < 8; ++r) {
            oh[r] = f2bf(tot[r]);
            ol[r] = f2bf(tot[r] - bf2f(oh[r]));
        }
        const size_t o = (size_t)n * H_DIM + col;
        *(ushort8*)(Oh + o) = oh;
        *(ushort8*)(Ol + o) = ol;
    }
}

// ---------------- split-bf16 MFMA GEMM, double-buffered prefetch ----------------
// C = ep(A @ W + bias); A hi/lo (M x K), W hi/lo transposed [N][K].
// 64x128 tile, BK=32, 4 waves 2x2 (32x64 each), mfma_f32_16x16x32_bf16,
// 3 MFMA terms (hi*hi + hi*lo + lo*hi).
// 2-phase pipeline: issue next tile's global_load_lds BEFORE current tile's
// frag-read+MFMA; trailing __syncthreads (compiler emits vmcnt(0)+barrier)
// drains the prefetch AFTER compute -> HBM latency hidden under MFMA.
// LDS 48KB -> 3 blocks/CU.

template <int DO_BN>
__global__ __launch_bounds__(256) void k_gemm_mfma(
    const ushort* __restrict__ Ah, const ushort* __restrict__ Al,
    const ushort* __restrict__ Wh, const ushort* __restrict__ Wlo,
    const float* __restrict__ bias,
    const float* __restrict__ g, const float* __restrict__ be,
    const float* __restrict__ rm, const float* __restrict__ rv,
    ushort* __restrict__ Oh, ushort* __restrict__ Ol,
    int K, int Nout) {
    __shared__ __align__(16) ushort As_h[2][64][32];
    __shared__ __align__(16) ushort As_l[2][64][32];
    __shared__ __align__(16) ushort Bs_h[2][128][32];
    __shared__ __align__(16) ushort Bs_l[2][128][32];

    const int tid  = threadIdx.x;
    const int lane = tid & 63;
    const int wid  = tid >> 6;
    const int wm   = wid >> 1, wn = wid & 1;
    const int bm = blockIdx.x * 64, bn = blockIdx.y * 128;
    const int rsel = lane & 15;
    const int kh   = (lane >> 4) * 8;

    f32x4 acc[2][4];
    #pragma unroll
    for (int m = 0; m < 2; ++m)
        #pragma unroll
        for (int n = 0; n < 4; ++n) {
            acc[m][n][0] = 0.f; acc[m][n][1] = 0.f;
            acc[m][n][2] = 0.f; acc[m][n][3] = 0.f;
        }

    auto stage = [&](int buf, int k0) {
        {
            const int off = tid * 16;          // A: 64x32 = 4KB/plane
            const int row = off >> 6;
            const int ke  = (off & 63) >> 1;
            const size_t ga = (size_t)(bm + row) * K + (k0 + ke);
            gload16(Ah + ga, (char*)&As_h[buf][0][0] + off);
            gload16(Al + ga, (char*)&As_l[buf][0][0] + off);
        }
        #pragma unroll
        for (int c = 0; c < 2; ++c) {
            const int off = tid * 16 + c * 4096;  // B: 128x32 = 8KB/plane
            const int row = off >> 6;
            const int ke  = (off & 63) >> 1;
            const size_t gb = (size_t)(bn + row) * K + (k0 + ke);
            gload16(Wh + gb,  (char*)&Bs_h[buf][0][0] + off);
            gload16(Wlo + gb, (char*)&Bs_l[buf][0][0] + off);
        }
    };

    stage(0, 0);
    __syncthreads();
    const int NT = K >> 5;
    for (int t = 0; t < NT; ++t) {
        const int cur = t & 1;
        if (t + 1 < NT) stage(cur ^ 1, (t + 1) << 5);   // prefetch next tile

        bf16x8 a_h[2], a_l[2], b_h[4], b_l[4];
        #pragma unroll
        for (int m = 0; m < 2; ++m) {
            const int r = wm * 32 + m * 16 + rsel;
            a_h[m] = *(const bf16x8*)&As_h[cur][r][kh];
            a_l[m] = *(const bf16x8*)&As_l[cur][r][kh];
        }
        #pragma unroll
        for (int n = 0; n < 4; ++n) {
            const int r = wn * 64 + n * 16 + rsel;
            b_h[n] = *(const bf16x8*)&Bs_h[cur][r][kh];
            b_l[n] = *(const bf16x8*)&Bs_l[cur][r][kh];
        }
        #pragma unroll
        for (int m = 0; m < 2; ++m)
            #pragma unroll
            for (int n = 0; n < 4; ++n) {
                acc[m][n] = __builtin_amdgcn_mfma_f32_16x16x32_bf16(a_h[m], b_h[n], acc[m][n], 0, 0, 0);
                acc[m][n] = __builtin_amdgcn_mfma_f32_16x16x32_bf16(a_h[m], b_l[n], acc[m][n], 0, 0, 0);
                acc[m][n] = __builtin_amdgcn_mfma_f32_16x16x32_bf16(a_l[m], b_h[n], acc[m][n], 0, 0, 0);
            }
        __syncthreads();   // drains this iteration's prefetch (vmcnt 0) + syncs buf reuse
    }

    float bs[4], sc[4], sh[4];
    int cols[4];
    #pragma unroll
    for (int n = 0; n < 4; ++n) {
        const int col = bn + wn * 64 + n * 16 + rsel;
        cols[n] = col;
        bs[n] = bias[col];
        if (DO_BN) {
            const float s = g[col] * rsqrtf(rv[col] + 1e-5f);
            sc[n] = s;
            sh[n] = be[col] - rm[col] * s;
        } else {
            sc[n] = 0.f; sh[n] = 0.f;
        }
    }
    #pragma unroll
    for (int m = 0; m < 2; ++m) {
        #pragma unroll
        for (int r = 0; r < 4; ++r) {
            const int row = bm + wm * 32 + m * 16 + (lane >> 4) * 4 + r;
            #pragma unroll
            for (int n = 0; n < 4; ++n) {
                float v = acc[m][n][r] + bs[n];
                v = fmaxf(v, 0.f);
                if (DO_BN) v = v * sc[n] + sh[n];
                const ushort hb = f2bf(v);
                const ushort lb = f2bf(v - bf2f(hb));
                const size_t o = (size_t)row * Nout + cols[n];
                Oh[o] = hb;
                Ol[o] = lb;
            }
        }
    }
}

// ---------------- edge head: out[t] = (h[a]*h[b]) @ Wf + bf ----------------

__global__ __launch_bounds__(256) void k_edge(
    const ushort* __restrict__ hh, const ushort* __restrict__ hl,
    const int* __restrict__ ei, const int* __restrict__ tids,
    const float* __restrict__ Wf, const float* __restrict__ bf_,
    float* __restrict__ out, int Etr, int E) {
    const int lane = threadIdx.x & 63;
    const int wv   = threadIdx.x >> 6;
    float wfr[8][N_CLS];
    #pragma unroll
    for (int r = 0; r < 8; ++r)
        #pragma unroll
        for (int c = 0; c < N_CLS; ++c)
            wfr[r][c] = Wf[(lane * 8 + r) * N_CLS + c];
    float bfr[N_CLS];
    #pragma unroll
    for (int c = 0; c < N_CLS; ++c) bfr[c] = bf_[c];

    const int wid  = blockIdx.x * 4 + wv;
    const int step = gridDim.x * 4;
    for (int t = wid; t < Etr; t += step) {
        const int eid = tids[t];
        const size_t a = (size_t)ei[eid] * H_DIM + lane * 8;
        const size_t b = (size_t)ei[E + eid] * H_DIM + lane * 8;
        const ushort8 ah = *(const ushort8*)(hh + a);
        const ushort8 al = *(const ushort8*)(hl + a);
        const ushort8 bh = *(const ushort8*)(hh + b);
        const ushort8 bl = *(const ushort8*)(hl + b);
        float acc[N_CLS] = {0.f, 0.f, 0.f, 0.f, 0.f, 0.f, 0.f};
        #pragma unroll
        for (int r = 0; r < 8; ++r) {
            const float va = bf2f(ah[r]) + bf2f(al[r]);
            const float vb = bf2f(bh[r]) + bf2f(bl[r]);
            const float e = va * vb;
            #pragma unroll
            for (int c = 0; c < N_CLS; ++c) acc[c] = fmaf(e, wfr[r][c], acc[c]);
        }
        #pragma unroll
        for (int o = 32; o; o >>= 1)
            #pragma unroll
            for (int c = 0; c < N_CLS; ++c) acc[c] += __shfl_xor(acc[c], o, 64);
        if (lane == 0) {
            #pragma unroll
            for (int c = 0; c < N_CLS; ++c) out[(size_t)t * N_CLS + c] = acc[c] + bfr[c];
        }
    }
}

// ---------------- launch ----------------

extern "C" void kernel_launch(void* const* d_in, const int* in_sizes, int n_in,
                              void* d_out, int out_size, void* d_ws, size_t ws_size,
                              hipStream_t stream) {
    const float* x    = (const float*)d_in[0];
    const int*   ei   = (const int*)d_in[1];
    const int*   tids = (const int*)d_in[2];
    const float* eps1 = (const float*)d_in[3];
    const float* W1a  = (const float*)d_in[4];
    const float* b1a  = (const float*)d_in[5];
    const float* W1b  = (const float*)d_in[6];
    const float* b1b  = (const float*)d_in[7];
    const float* g1p  = (const float*)d_in[8];
    const float* be1  = (const float*)d_in[9];
    const float* rm1  = (const float*)d_in[10];
    const float* rv1  = (const float*)d_in[11];
    const float* eps2 = (const float*)d_in[12];
    const float* W2a  = (const float*)d_in[13];
    const float* b2a  = (const float*)d_in[14];
    const float* g2p  = (const float*)d_in[15];
    const float* be2  = (const float*)d_in[16];
    const float* rm2  = (const float*)d_in[17];
    const float* rv2  = (const float*)d_in[18];
    const float* Wl   = (const float*)d_in[19];
    const float* bl   = (const float*)d_in[20];
    const float* Wf   = (const float*)d_in[21];
    const float* bf   = (const float*)d_in[22];
    float* out = (float*)d_out;

    const int E   = in_sizes[1] / 2;
    const int Etr = in_sizes[2];

    char* ws = (char*)d_ws;
    size_t off = 0;
    auto alloc = [&](size_t bytes) -> char* {
        char* p = ws + off;
        off += (bytes + 255) & ~(size_t)255;
        return p;
    };
    int*    counts  = (int*)alloc((size_t)N_NODES * 4);
    int*    offsets = (int*)alloc((size_t)(N_NODES + 1) * 4);
    int*    cursor  = (int*)alloc((size_t)N_NODES * 4);
    int*    csr_src = (int*)alloc((size_t)E * 4);
    ushort* h0h = (ushort*)alloc((size_t)M_PAD * F_IN * 2);
    ushort* h0l = (ushort*)alloc((size_t)M_PAD * F_IN * 2);
    ushort* Ahh = (ushort*)alloc((size_t)M_PAD * H_DIM * 2);  // pair A
    ushort* Ahl = (ushort*)alloc((size_t)M_PAD * H_DIM * 2);
    ushort* Bhh = (ushort*)alloc((size_t)M_PAD * H_DIM * 2);  // pair B
    ushort* Bhl = (ushort*)alloc((size_t)M_PAD * H_DIM * 2);
    ushort* wt1a_h = (ushort*)alloc((size_t)H_DIM * F_IN * 2);
    ushort* wt1a_l = (ushort*)alloc((size_t)H_DIM * F_IN * 2);
    ushort* wt1b_h = (ushort*)alloc((size_t)H_DIM * H_DIM * 2);
    ushort* wt1b_l = (ushort*)alloc((size_t)H_DIM * H_DIM * 2);
    ushort* wt2a_h = (ushort*)alloc((size_t)H_DIM * H_DIM * 2);
    ushort* wt2a_l = (ushort*)alloc((size_t)H_DIM * H_DIM * 2);
    ushort* wtl_h  = (ushort*)alloc((size_t)H_DIM * H_DIM * 2);
    ushort* wtl_l  = (ushort*)alloc((size_t)H_DIM * H_DIM * 2);
    (void)ws_size; (void)n_in; (void)out_size;

    // CSR by dst
    k_zero_i32<<<(N_NODES + 255) / 256, 256, 0, stream>>>(counts, N_NODES);
    k_hist<<<(E + 255) / 256, 256, 0, stream>>>(ei, counts, E);
    k_scan<<<1, 1024, 0, stream>>>(counts, offsets, cursor, N_NODES, E);
    k_scatter<<<(E + 255) / 256, 256, 0, stream>>>(ei, cursor, csr_src, E);

    // weight hi/lo transposed splits (LDS-tile transpose, coalesced both sides)
    k_wsplit<<<dim3(F_IN / 32, H_DIM / 32), 256, 0, stream>>>(W1a, wt1a_h, wt1a_l, F_IN, H_DIM);
    k_wsplit<<<dim3(H_DIM / 32, H_DIM / 32), 256, 0, stream>>>(W1b, wt1b_h, wt1b_l, H_DIM, H_DIM);
    k_wsplit<<<dim3(H_DIM / 32, H_DIM / 32), 256, 0, stream>>>(W2a, wt2a_h, wt2a_l, H_DIM, H_DIM);
    k_wsplit<<<dim3(H_DIM / 32, H_DIM / 32), 256, 0, stream>>>(Wl,  wtl_h,  wtl_l,  H_DIM, H_DIM);

    // h0 = (1+eps1)*x + agg(x)  -> pair (wave per node, 4 nodes/block)
    k_agg_f32<<<(N_NODES + 3) / 4, 256, 0, stream>>>(x, csr_src, offsets, eps1, h0h, h0l);

    dim3 gdim(M_PAD / 64, H_DIM / 128);   // 158 x 4 = 632 blocks
    // h1 = relu(h0 @ W1a + b1a)            -> pair A
    k_gemm_mfma<0><<<gdim, 256, 0, stream>>>(h0h, h0l, wt1a_h, wt1a_l, b1a,
                                             nullptr, nullptr, nullptr, nullptr,
                                             Ahh, Ahl, F_IN, H_DIM);
    // h2 = bn1(relu(h1 @ W1b + b1b))       -> pair B
    k_gemm_mfma<1><<<gdim, 256, 0, stream>>>(Ahh, Ahl, wt1b_h, wt1b_l, b1b,
                                             g1p, be1, rm1, rv1,
                                             Bhh, Bhl, H_DIM, H_DIM);
    // h3 = (1+eps2)*h2 + agg(h2)           -> pair A (XCD column-chunked)
    k_agg_pair<<<(N_NODES / 16) * NCHUNK, 256, 0, stream>>>(Bhh, Bhl, csr_src, offsets, eps2, Ahh, Ahl);
    // h4 = bn2(relu(h3 @ W2a + b2a))       -> pair B
    k_gemm_mfma<1><<<gdim, 256, 0, stream>>>(Ahh, Ahl, wt2a_h, wt2a_l, b2a,
                                             g2p, be2, rm2, rv2,
                                             Bhh, Bhl, H_DIM, H_DIM);
    // h5 = relu(h4 @ Wl + bl)              -> pair A
    k_gemm_mfma<0><<<gdim, 256, 0, stream>>>(Bhh, Bhl, wtl_h, wtl_l, bl,
                                             nullptr, nullptr, nullptr, nullptr,
                                             Ahh, Ahl, H_DIM, H_DIM);
    // edge head (grid-stride, wf-in-registers)
    k_edge<<<2048, 256, 0, stream>>>(Ahh, Ahl, ei, tids, Wf, bf, out, Etr, E);
}